// Round 2
// baseline (1224.414 us; speedup 1.0000x reference)
//
#include <hip/hip_runtime.h>
#include <math.h>

#define NN 20000
#define EE 320000
#define ET (EE + NN)

// ---------------- CSR construction ----------------
__global__ void count_init(int* cnt) {
    int n = blockIdx.x * blockDim.x + threadIdx.x;
    if (n < NN) cnt[n] = 1;  // self-loop
}

__global__ void count_edges(const int* dst, int* cnt) {
    int e = blockIdx.x * blockDim.x + threadIdx.x;
    if (e < EE) atomicAdd(&cnt[dst[e]], 1);
}

__global__ void scan_kernel(const int* cnt, int* indptr, int* cursor) {
    __shared__ int part[1024];
    int tid = threadIdx.x;
    const int CH = 20;  // 1024*20 = 20480 >= NN
    int base = tid * CH;
    int sum = 0;
    for (int i = 0; i < CH; i++) {
        int idx = base + i;
        if (idx < NN) sum += cnt[idx];
    }
    part[tid] = sum;
    __syncthreads();
    for (int off = 1; off < 1024; off <<= 1) {
        int v = (tid >= off) ? part[tid - off] : 0;
        __syncthreads();
        part[tid] += v;
        __syncthreads();
    }
    int run = (tid == 0) ? 0 : part[tid - 1];
    for (int i = 0; i < CH; i++) {
        int idx = base + i;
        if (idx < NN) {
            indptr[idx] = run;
            cursor[idx] = run;
            run += cnt[idx];
        }
    }
    if (tid == 1023) indptr[NN] = run;  // = ET
}

__global__ void scatter_self(int* cursor, int* esrc) {
    int n = blockIdx.x * blockDim.x + threadIdx.x;
    if (n < NN) {
        int pos = atomicAdd(&cursor[n], 1);
        esrc[pos] = n;
    }
}

__global__ void scatter_edges(const int* src, const int* dst, int* cursor, int* esrc) {
    int e = blockIdx.x * blockDim.x + threadIdx.x;
    if (e < EE) {
        int pos = atomicAdd(&cursor[dst[e]], 1);
        esrc[pos] = src[e];
    }
}

// ---------------- generic tiled fp32 GEMM: C = A*B (+bias)(+relu) ----------------
// A [M,K] row-major lda; B [K,N] row-major ldb; C [M,N] row-major ldc.
// Requires K % 16 == 0, N % 64 == 0. M arbitrary.
__global__ __launch_bounds__(256) void gemm_kernel(
    const float* __restrict__ A, int lda,
    const float* __restrict__ B, int ldb,
    float* __restrict__ C, int ldc,
    int M, int N, int K,
    const float* __restrict__ bias, int relu)
{
    __shared__ float As[16][65];
    __shared__ float Bs[16][64];
    int tid = threadIdx.x;
    int tx = tid % 16, ty = tid / 16;
    int row0 = blockIdx.y * 64, col0 = blockIdx.x * 64;
    float acc[4][4] = {};
    for (int k0 = 0; k0 < K; k0 += 16) {
        #pragma unroll
        for (int i = 0; i < 4; i++) {
            int idx = tid + i * 256;      // 0..1023
            int r = idx >> 4;             // 0..63
            int kk = idx & 15;
            int gr = row0 + r;
            float v = 0.f;
            if (gr < M) v = A[(long)gr * lda + k0 + kk];
            As[kk][r] = v;
        }
        #pragma unroll
        for (int i = 0; i < 4; i++) {
            int idx = tid + i * 256;
            int kk = idx >> 6;            // 0..15
            int c = idx & 63;
            Bs[kk][c] = B[(long)(k0 + kk) * ldb + col0 + c];
        }
        __syncthreads();
        #pragma unroll
        for (int kk = 0; kk < 16; kk++) {
            float a[4], b[4];
            #pragma unroll
            for (int i = 0; i < 4; i++) a[i] = As[kk][ty * 4 + i];
            #pragma unroll
            for (int j = 0; j < 4; j++) b[j] = Bs[kk][tx * 4 + j];
            #pragma unroll
            for (int i = 0; i < 4; i++)
                #pragma unroll
                for (int j = 0; j < 4; j++) acc[i][j] += a[i] * b[j];
        }
        __syncthreads();
    }
    #pragma unroll
    for (int i = 0; i < 4; i++) {
        int r = row0 + ty * 4 + i;
        if (r >= M) continue;
        #pragma unroll
        for (int j = 0; j < 4; j++) {
            int c = col0 + tx * 4 + j;
            float v = acc[i][j] + (bias ? bias[c] : 0.f);
            if (relu) v = fmaxf(v, 0.f);
            C[(long)r * ldc + c] = v;
        }
    }
}

// ---------------- attention logits: al[n,h] = <h[n,h,:], a_src[h,:]> ----------------
__global__ __launch_bounds__(256) void logits_kernel(
    const float* __restrict__ hbuf,
    const float* __restrict__ a_src, const float* __restrict__ a_dst,
    float* __restrict__ al, float* __restrict__ ar)
{
    int n = blockIdx.x;             // node
    int h = threadIdx.x >> 6;       // head (wave)
    int lane = threadIdx.x & 63;    // channel
    float v = hbuf[(long)n * 256 + h * 64 + lane];
    float ps = v * a_src[h * 64 + lane];
    float pd = v * a_dst[h * 64 + lane];
    #pragma unroll
    for (int off = 32; off; off >>= 1) {
        ps += __shfl_xor(ps, off);
        pd += __shfl_xor(pd, off);
    }
    if (lane == 0) {
        al[n * 4 + h] = ps;
        ar[n * 4 + h] = pd;
    }
}

// ---------------- GAT aggregation: block per node, wave per head, lane per channel ----------------
__global__ __launch_bounds__(256) void aggregate_kernel(
    const float* __restrict__ hbuf,
    const float* __restrict__ al, const float* __restrict__ ar,
    const int* __restrict__ indptr, const int* __restrict__ esrc,
    const float* __restrict__ bias,
    float* __restrict__ out, int ldo)
{
    int n = blockIdx.x;
    int h = threadIdx.x >> 6;
    int lane = threadIdx.x & 63;
    int beg = indptr[n], end = indptr[n + 1];
    float arn = ar[n * 4 + h];
    // pass 1: max over incoming edges (lane-parallel)
    float mloc = -1e30f;
    for (int j = beg + lane; j < end; j += 64) {
        float e = al[esrc[j] * 4 + h] + arn;
        e = e > 0.f ? e : 0.2f * e;
        mloc = fmaxf(mloc, e);
    }
    #pragma unroll
    for (int off = 32; off; off >>= 1) mloc = fmaxf(mloc, __shfl_xor(mloc, off));
    float m = mloc;
    // pass 2: serial over edges, lanes carry channels
    float ssum = 0.f, acc = 0.f;
    for (int j = beg; j < end; j++) {
        int s = esrc[j];
        float e = al[s * 4 + h] + arn;   // broadcast load
        e = e > 0.f ? e : 0.2f * e;
        float ex = __expf(e - m);
        ssum += ex;
        acc += ex * hbuf[(long)s * 256 + h * 64 + lane];
    }
    out[(long)n * ldo + h * 64 + lane] = acc / (ssum + 1e-16f) + bias[h * 64 + lane];
}

// ---------------- output gathers ----------------
__global__ void gather_feats(const float* __restrict__ Bf, const float* __restrict__ Tf,
                             const int* __restrict__ voc, const int* __restrict__ batch,
                             float* __restrict__ out)
{
    int i = blockIdx.x * blockDim.x + threadIdx.x;
    if (i < NN * 128) {
        int n = i >> 7, c = i & 127;
        int t = voc[n];
        out[i] = Bf[(long)t * 128 + c];
        out[(long)NN * 128 + i] = Tf[(long)t * 128 + c];
    }
    if (i < NN) out[(long)NN * 128 * 2 + (long)NN * 64 + i] = (float)batch[i];
}

// ---------------- host-side orchestration ----------------
extern "C" void kernel_launch(void* const* d_in, const int* in_sizes, int n_in,
                              void* d_out, int out_size, void* d_ws, size_t ws_size,
                              hipStream_t stream) {
    const float* x     = (const float*)d_in[0];
    const int*   ei    = (const int*)d_in[1];
    const int*   batch = (const int*)d_in[2];
    const int*   voc   = (const int*)d_in[3];
    const float* Bf    = (const float*)d_in[4];
    const float* Tf    = (const float*)d_in[5];
    const float* W0    = (const float*)d_in[6];
    const float* as0   = (const float*)d_in[7];
    const float* ad0   = (const float*)d_in[8];
    const float* b0    = (const float*)d_in[9];
    const float* W1    = (const float*)d_in[10];
    const float* as1   = (const float*)d_in[11];
    const float* ad1   = (const float*)d_in[12];
    const float* b1    = (const float*)d_in[13];
    const float* W2    = (const float*)d_in[14];
    const float* as2   = (const float*)d_in[15];
    const float* ad2   = (const float*)d_in[16];
    const float* b2    = (const float*)d_in[17];
    const float* fcmax_w = (const float*)d_in[18];
    const float* fcmax_b = (const float*)d_in[19];
    const float* fc1_w = (const float*)d_in[20];
    const float* fc1_b = (const float*)d_in[21];
    const float* fc2_w = (const float*)d_in[22];
    const float* fc2_b = (const float*)d_in[23];
    const float* fc3_w = (const float*)d_in[24];
    const float* fc3_b = (const float*)d_in[25];
    float* out = (float*)d_out;

    char* p = (char*)d_ws;
    float* hbuf = (float*)p; p += (size_t)NN * 256 * 4;    // 20.5 MB
    float* z    = (float*)p; p += (size_t)NN * 1536 * 4;   // 122.9 MB
    float* z1   = (float*)p; p += (size_t)NN * 512 * 4;    // 41 MB
    float* al   = (float*)p; p += (size_t)NN * 4 * 4;
    float* ar   = (float*)p; p += (size_t)NN * 4 * 4;
    int* cnt    = (int*)p;   p += (size_t)NN * 4;
    int* indptr = (int*)p;   p += (size_t)(NN + 1) * 4;
    int* cursor = (int*)p;   p += (size_t)NN * 4;
    int* esrc   = (int*)p;   p += (size_t)ET * 4;

    const int* e_src = ei;
    const int* e_dst = ei + EE;

    // CSR (dst-sorted incoming edges, incl. self-loops) — reused by all 3 layers
    count_init<<<(NN + 255) / 256, 256, 0, stream>>>(cnt);
    count_edges<<<(EE + 255) / 256, 256, 0, stream>>>(e_dst, cnt);
    scan_kernel<<<1, 1024, 0, stream>>>(cnt, indptr, cursor);
    scatter_self<<<(NN + 255) / 256, 256, 0, stream>>>(cursor, esrc);
    scatter_edges<<<(EE + 255) / 256, 256, 0, stream>>>(e_src, e_dst, cursor, esrc);

    // independent output gathers (b_sel, t_sel, batch)
    gather_feats<<<(NN * 128 + 255) / 256, 256, 0, stream>>>(Bf, Tf, voc, batch, out);

    const int MB = (NN + 63) / 64;  // 313

    // ---- GAT layer 0 ----
    gemm_kernel<<<dim3(4, MB), 256, 0, stream>>>(x, 128, W0, 256, hbuf, 256, NN, 256, 128, nullptr, 0);
    logits_kernel<<<NN, 256, 0, stream>>>(hbuf, as0, ad0, al, ar);
    aggregate_kernel<<<NN, 256, 0, stream>>>(hbuf, al, ar, indptr, esrc, b0, z + 0, 1536);
    gemm_kernel<<<dim3(4, MB), 256, 0, stream>>>(z + 0, 1536, fcmax_w, 256, z + 256, 1536, NN, 256, 256, fcmax_b, 1);

    // ---- GAT layer 1 ----
    gemm_kernel<<<dim3(4, MB), 256, 0, stream>>>(z + 256, 1536, W1, 256, hbuf, 256, NN, 256, 256, nullptr, 0);
    logits_kernel<<<NN, 256, 0, stream>>>(hbuf, as1, ad1, al, ar);
    aggregate_kernel<<<NN, 256, 0, stream>>>(hbuf, al, ar, indptr, esrc, b1, z + 512, 1536);
    gemm_kernel<<<dim3(4, MB), 256, 0, stream>>>(z + 512, 1536, fcmax_w, 256, z + 768, 1536, NN, 256, 256, fcmax_b, 1);

    // ---- GAT layer 2 ----
    gemm_kernel<<<dim3(4, MB), 256, 0, stream>>>(z + 768, 1536, W2, 256, hbuf, 256, NN, 256, 256, nullptr, 0);
    logits_kernel<<<NN, 256, 0, stream>>>(hbuf, as2, ad2, al, ar);
    aggregate_kernel<<<NN, 256, 0, stream>>>(hbuf, al, ar, indptr, esrc, b2, z + 1024, 1536);
    gemm_kernel<<<dim3(4, MB), 256, 0, stream>>>(z + 1024, 1536, fcmax_w, 256, z + 1280, 1536, NN, 256, 256, fcmax_b, 1);

    // ---- MLP head ----
    gemm_kernel<<<dim3(8, MB), 256, 0, stream>>>(z, 1536, fc1_w, 512, z1, 512, NN, 512, 1536, fc1_b, 1);
    gemm_kernel<<<dim3(2, MB), 256, 0, stream>>>(z1, 512, fc2_w, 128, hbuf, 128, NN, 128, 512, fc2_b, 1);
    gemm_kernel<<<dim3(1, MB), 256, 0, stream>>>(hbuf, 128, fc3_w, 64, out + (size_t)2 * NN * 128, 64, NN, 64, 128, fc3_b, 0);
}

// Round 3
// 724.794 us; speedup vs baseline: 1.6893x; 1.6893x over previous
//
#include <hip/hip_runtime.h>
#include <math.h>

#define NN 20000
#define EE 320000
#define ET (EE + NN)

typedef __attribute__((ext_vector_type(8))) short bf16x8;
typedef __attribute__((ext_vector_type(4))) float f32x4;
typedef __attribute__((ext_vector_type(4))) unsigned short us4;
typedef __attribute__((ext_vector_type(8))) unsigned short us8;
typedef __attribute__((ext_vector_type(4))) float fx4;

__device__ inline unsigned short f2bf(float f) {
    union { float f; unsigned u; } x; x.f = f;
    unsigned u = x.u;
    return (unsigned short)((u + 0x7FFF + ((u >> 16) & 1)) >> 16);
}

__device__ inline void storeC(float* C, size_t idx, float v) { C[idx] = v; }
__device__ inline void storeC(unsigned short* C, size_t idx, float v) { C[idx] = f2bf(v); }

// ---------------- CSR construction ----------------
__global__ void count_init(int* cnt) {
    int n = blockIdx.x * blockDim.x + threadIdx.x;
    if (n < NN) cnt[n] = 1;  // self-loop
}

__global__ void count_edges(const int* dst, int* cnt) {
    int e = blockIdx.x * blockDim.x + threadIdx.x;
    if (e < EE) atomicAdd(&cnt[dst[e]], 1);
}

__global__ void scan_kernel(const int* cnt, int* indptr, int* cursor) {
    __shared__ int part[1024];
    int tid = threadIdx.x;
    const int CH = 20;
    int base = tid * CH;
    int sum = 0;
    for (int i = 0; i < CH; i++) {
        int idx = base + i;
        if (idx < NN) sum += cnt[idx];
    }
    part[tid] = sum;
    __syncthreads();
    for (int off = 1; off < 1024; off <<= 1) {
        int v = (tid >= off) ? part[tid - off] : 0;
        __syncthreads();
        part[tid] += v;
        __syncthreads();
    }
    int run = (tid == 0) ? 0 : part[tid - 1];
    for (int i = 0; i < CH; i++) {
        int idx = base + i;
        if (idx < NN) {
            indptr[idx] = run;
            cursor[idx] = run;
            run += cnt[idx];
        }
    }
    if (tid == 1023) indptr[NN] = run;
}

__global__ void scatter_self(int* cursor, int* esrc) {
    int n = blockIdx.x * blockDim.x + threadIdx.x;
    if (n < NN) {
        int pos = atomicAdd(&cursor[n], 1);
        esrc[pos] = n;
    }
}

__global__ void scatter_edges(const int* src, const int* dst, int* cursor, int* esrc) {
    int e = blockIdx.x * blockDim.x + threadIdx.x;
    if (e < EE) {
        int pos = atomicAdd(&cursor[dst[e]], 1);
        esrc[pos] = src[e];
    }
}

// ---------------- bf16 MFMA GEMM: C = A*B (+bias)(+relu) ----------------
// A [M,K] (float or bf16) row-major lda; B [K,N] fp32 row-major ldb;
// C [M,N] (float or bf16) row-major ldc. K%64==0, N%BN==0. M arbitrary.
// BM=128, BK=64, 256 threads = 4 waves, each wave owns 32 x BN.
template <int BN, typename TA, typename TC>
__global__ __launch_bounds__(256) void mfma_gemm(
    const TA* __restrict__ A, int lda,
    const float* __restrict__ B, int ldb,
    TC* __restrict__ C, int ldc,
    int M, int K,
    const float* __restrict__ bias, int relu)
{
    constexpr int BM = 128, BK = 64, LDS_ROW = BK + 8;  // pad 8 bf16 -> 144B stride
    constexpr int NJ = BN / 16;
    __shared__ unsigned short Als[BM * LDS_ROW];
    __shared__ unsigned short Bls[BN * LDS_ROW];

    int tid = threadIdx.x;
    int lane = tid & 63, w = tid >> 6;
    int row0 = blockIdx.y * BM, col0 = blockIdx.x * BN;

    f32x4 acc[2][NJ];
    #pragma unroll
    for (int i = 0; i < 2; i++)
        #pragma unroll
        for (int j = 0; j < NJ; j++) acc[i][j] = (f32x4){0.f, 0.f, 0.f, 0.f};

    for (int k0 = 0; k0 < K; k0 += BK) {
        // ---- stage A -> LDS (convert to bf16 if fp32) ----
        if constexpr (sizeof(TA) == 4) {
            #pragma unroll
            for (int i = 0; i < 8; i++) {
                int e = i * 1024 + tid * 4;
                int r = e >> 6, c = e & 63;
                int gr = row0 + r;
                fx4 v = (fx4){0.f, 0.f, 0.f, 0.f};
                if (gr < M) v = *(const fx4*)((const float*)A + (size_t)gr * lda + k0 + c);
                us4 s;
                #pragma unroll
                for (int j = 0; j < 4; j++) s[j] = f2bf(v[j]);
                *(us4*)&Als[r * LDS_ROW + c] = s;
            }
        } else {
            #pragma unroll
            for (int i = 0; i < 4; i++) {
                int e = i * 2048 + tid * 8;
                int r = e >> 6, c = e & 63;
                int gr = row0 + r;
                us8 v = (us8){0, 0, 0, 0, 0, 0, 0, 0};
                if (gr < M) v = *(const us8*)((const unsigned short*)A + (size_t)gr * lda + k0 + c);
                *(us8*)&Als[r * LDS_ROW + c] = v;
            }
        }
        // ---- stage B -> LDS transposed [n][k] ----
        {
            int n = tid & 63, kg = tid >> 6;
            #pragma unroll
            for (int p = 0; p < BN / 64; p++) {
                int nn = n + p * 64;
                #pragma unroll
                for (int i = 0; i < 4; i++) {
                    int kb = kg * 4 + i * 16;
                    us4 s;
                    #pragma unroll
                    for (int j = 0; j < 4; j++)
                        s[j] = f2bf(B[(size_t)(k0 + kb + j) * ldb + col0 + nn]);
                    *(us4*)&Bls[nn * LDS_ROW + kb] = s;
                }
            }
        }
        __syncthreads();
        // ---- MFMA over the K-tile ----
        #pragma unroll
        for (int kc = 0; kc < 2; kc++) {
            int koff = kc * 32 + (lane >> 4) * 8;
            bf16x8 af[2];
            #pragma unroll
            for (int i = 0; i < 2; i++)
                af[i] = *(bf16x8*)&Als[(w * 32 + i * 16 + (lane & 15)) * LDS_ROW + koff];
            bf16x8 bfr[NJ];
            #pragma unroll
            for (int j = 0; j < NJ; j++)
                bfr[j] = *(bf16x8*)&Bls[(j * 16 + (lane & 15)) * LDS_ROW + koff];
            #pragma unroll
            for (int i = 0; i < 2; i++)
                #pragma unroll
                for (int j = 0; j < NJ; j++)
                    acc[i][j] = __builtin_amdgcn_mfma_f32_16x16x32_bf16(af[i], bfr[j], acc[i][j], 0, 0, 0);
        }
        __syncthreads();
    }
    // ---- epilogue: bias + relu, store ----
    #pragma unroll
    for (int i = 0; i < 2; i++) {
        #pragma unroll
        for (int r = 0; r < 4; r++) {
            int row = row0 + w * 32 + i * 16 + ((lane >> 4) << 2) + r;
            if (row >= M) continue;
            #pragma unroll
            for (int j = 0; j < NJ; j++) {
                int col = col0 + j * 16 + (lane & 15);
                float v = acc[i][j][r] + (bias ? bias[col] : 0.f);
                if (relu) v = fmaxf(v, 0.f);
                storeC(C, (size_t)row * ldc + col, v);
            }
        }
    }
}

// ---------------- attention logits ----------------
__global__ __launch_bounds__(256) void logits_kernel(
    const float* __restrict__ hbuf,
    const float* __restrict__ a_src, const float* __restrict__ a_dst,
    float* __restrict__ al, float* __restrict__ ar)
{
    int n = blockIdx.x;
    int h = threadIdx.x >> 6;
    int lane = threadIdx.x & 63;
    float v = hbuf[(long)n * 256 + h * 64 + lane];
    float ps = v * a_src[h * 64 + lane];
    float pd = v * a_dst[h * 64 + lane];
    #pragma unroll
    for (int off = 32; off; off >>= 1) {
        ps += __shfl_xor(ps, off);
        pd += __shfl_xor(pd, off);
    }
    if (lane == 0) {
        al[n * 4 + h] = ps;
        ar[n * 4 + h] = pd;
    }
}

// ---------------- GAT aggregation (bf16 out into z slice) ----------------
__global__ __launch_bounds__(256) void aggregate_kernel(
    const float* __restrict__ hbuf,
    const float* __restrict__ al, const float* __restrict__ ar,
    const int* __restrict__ indptr, const int* __restrict__ esrc,
    const float* __restrict__ bias,
    unsigned short* __restrict__ out, int ldo)
{
    int n = blockIdx.x;
    int h = threadIdx.x >> 6;
    int lane = threadIdx.x & 63;
    int beg = indptr[n], end = indptr[n + 1];
    float arn = ar[n * 4 + h];
    float mloc = -1e30f;
    for (int j = beg + lane; j < end; j += 64) {
        float e = al[esrc[j] * 4 + h] + arn;
        e = e > 0.f ? e : 0.2f * e;
        mloc = fmaxf(mloc, e);
    }
    #pragma unroll
    for (int off = 32; off; off >>= 1) mloc = fmaxf(mloc, __shfl_xor(mloc, off));
    float m = mloc;
    float ssum = 0.f, acc = 0.f;
    for (int j = beg; j < end; j++) {
        int s = esrc[j];
        float e = al[s * 4 + h] + arn;
        e = e > 0.f ? e : 0.2f * e;
        float ex = __expf(e - m);
        ssum += ex;
        acc += ex * hbuf[(long)s * 256 + h * 64 + lane];
    }
    float v = acc / (ssum + 1e-16f) + bias[h * 64 + lane];
    out[(long)n * ldo + h * 64 + lane] = f2bf(v);
}

// ---------------- output gathers ----------------
__global__ void gather_feats(const float* __restrict__ Bf, const float* __restrict__ Tf,
                             const int* __restrict__ voc, const int* __restrict__ batch,
                             float* __restrict__ out)
{
    int i = blockIdx.x * blockDim.x + threadIdx.x;
    if (i < NN * 128) {
        int n = i >> 7, c = i & 127;
        int t = voc[n];
        out[i] = Bf[(long)t * 128 + c];
        out[(long)NN * 128 + i] = Tf[(long)t * 128 + c];
    }
    if (i < NN) out[(long)NN * 128 * 2 + (long)NN * 64 + i] = (float)batch[i];
}

// ---------------- host-side orchestration ----------------
extern "C" void kernel_launch(void* const* d_in, const int* in_sizes, int n_in,
                              void* d_out, int out_size, void* d_ws, size_t ws_size,
                              hipStream_t stream) {
    const float* x     = (const float*)d_in[0];
    const int*   ei    = (const int*)d_in[1];
    const int*   batch = (const int*)d_in[2];
    const int*   voc   = (const int*)d_in[3];
    const float* Bf    = (const float*)d_in[4];
    const float* Tf    = (const float*)d_in[5];
    const float* W0    = (const float*)d_in[6];
    const float* as0   = (const float*)d_in[7];
    const float* ad0   = (const float*)d_in[8];
    const float* b0    = (const float*)d_in[9];
    const float* W1    = (const float*)d_in[10];
    const float* as1   = (const float*)d_in[11];
    const float* ad1   = (const float*)d_in[12];
    const float* b1    = (const float*)d_in[13];
    const float* W2    = (const float*)d_in[14];
    const float* as2   = (const float*)d_in[15];
    const float* ad2   = (const float*)d_in[16];
    const float* b2    = (const float*)d_in[17];
    const float* fcmax_w = (const float*)d_in[18];
    const float* fcmax_b = (const float*)d_in[19];
    const float* fc1_w = (const float*)d_in[20];
    const float* fc1_b = (const float*)d_in[21];
    const float* fc2_w = (const float*)d_in[22];
    const float* fc2_b = (const float*)d_in[23];
    const float* fc3_w = (const float*)d_in[24];
    const float* fc3_b = (const float*)d_in[25];
    float* out = (float*)d_out;

    char* p = (char*)d_ws;
    float* hbuf = (float*)p;          p += (size_t)NN * 256 * 4;   // fp32 GAT h
    unsigned short* z  = (unsigned short*)p; p += (size_t)NN * 1536 * 2;  // bf16 concat
    unsigned short* z1 = (unsigned short*)p; p += (size_t)NN * 512 * 2;   // bf16 fc1 out
    unsigned short* h2 = (unsigned short*)p; p += (size_t)NN * 128 * 2;   // bf16 fc2 out
    float* al   = (float*)p; p += (size_t)NN * 4 * 4;
    float* ar   = (float*)p; p += (size_t)NN * 4 * 4;
    int* cnt    = (int*)p;   p += (size_t)NN * 4;
    int* indptr = (int*)p;   p += (size_t)(NN + 1) * 4;
    int* cursor = (int*)p;   p += (size_t)NN * 4;
    int* esrc   = (int*)p;   p += (size_t)ET * 4;

    const int* e_src = ei;
    const int* e_dst = ei + EE;

    // CSR (dst-sorted incoming edges, incl. self-loops) — reused by all 3 layers
    count_init<<<(NN + 255) / 256, 256, 0, stream>>>(cnt);
    count_edges<<<(EE + 255) / 256, 256, 0, stream>>>(e_dst, cnt);
    scan_kernel<<<1, 1024, 0, stream>>>(cnt, indptr, cursor);
    scatter_self<<<(NN + 255) / 256, 256, 0, stream>>>(cursor, esrc);
    scatter_edges<<<(EE + 255) / 256, 256, 0, stream>>>(e_src, e_dst, cursor, esrc);

    // independent output gathers (b_sel, t_sel, batch)
    gather_feats<<<(NN * 128 + 255) / 256, 256, 0, stream>>>(Bf, Tf, voc, batch, out);

    const int MB = (NN + 127) / 128;  // 157

    // ---- GAT layer 0 ----
    mfma_gemm<128, float, float><<<dim3(2, MB), 256, 0, stream>>>(x, 128, W0, 256, hbuf, 256, NN, 128, nullptr, 0);
    logits_kernel<<<NN, 256, 0, stream>>>(hbuf, as0, ad0, al, ar);
    aggregate_kernel<<<NN, 256, 0, stream>>>(hbuf, al, ar, indptr, esrc, b0, z + 0, 1536);
    mfma_gemm<128, unsigned short, unsigned short><<<dim3(2, MB), 256, 0, stream>>>(z + 0, 1536, fcmax_w, 256, z + 256, 1536, NN, 256, fcmax_b, 1);

    // ---- GAT layer 1 ----
    mfma_gemm<128, unsigned short, float><<<dim3(2, MB), 256, 0, stream>>>(z + 256, 1536, W1, 256, hbuf, 256, NN, 256, nullptr, 0);
    logits_kernel<<<NN, 256, 0, stream>>>(hbuf, as1, ad1, al, ar);
    aggregate_kernel<<<NN, 256, 0, stream>>>(hbuf, al, ar, indptr, esrc, b1, z + 512, 1536);
    mfma_gemm<128, unsigned short, unsigned short><<<dim3(2, MB), 256, 0, stream>>>(z + 512, 1536, fcmax_w, 256, z + 768, 1536, NN, 256, fcmax_b, 1);

    // ---- GAT layer 2 ----
    mfma_gemm<128, unsigned short, float><<<dim3(2, MB), 256, 0, stream>>>(z + 768, 1536, W2, 256, hbuf, 256, NN, 256, nullptr, 0);
    logits_kernel<<<NN, 256, 0, stream>>>(hbuf, as2, ad2, al, ar);
    aggregate_kernel<<<NN, 256, 0, stream>>>(hbuf, al, ar, indptr, esrc, b2, z + 1024, 1536);
    mfma_gemm<128, unsigned short, unsigned short><<<dim3(2, MB), 256, 0, stream>>>(z + 1024, 1536, fcmax_w, 256, z + 1280, 1536, NN, 256, fcmax_b, 1);

    // ---- MLP head ----
    mfma_gemm<128, unsigned short, unsigned short><<<dim3(4, MB), 256, 0, stream>>>(z, 1536, fc1_w, 512, z1, 512, NN, 1536, fc1_b, 1);
    mfma_gemm<128, unsigned short, unsigned short><<<dim3(1, MB), 256, 0, stream>>>(z1, 512, fc2_w, 128, h2, 128, NN, 512, fc2_b, 1);
    mfma_gemm<64, unsigned short, float><<<dim3(1, MB), 256, 0, stream>>>(h2, 128, fc3_w, 64, out + (size_t)2 * NN * 128, 64, NN, 128, fc3_b, 0);
}

// Round 4
// 655.053 us; speedup vs baseline: 1.8692x; 1.1065x over previous
//
#include <hip/hip_runtime.h>
#include <math.h>

#define NN 20000
#define EE 320000
#define ET (EE + NN)

typedef __attribute__((ext_vector_type(8))) short bf16x8;
typedef __attribute__((ext_vector_type(4))) float f32x4;
typedef __attribute__((ext_vector_type(4))) unsigned short us4;
typedef __attribute__((ext_vector_type(8))) unsigned short us8;
typedef __attribute__((ext_vector_type(4))) float fx4;

__device__ inline unsigned short f2bf(float f) {
    union { float f; unsigned u; } x; x.f = f;
    unsigned u = x.u;
    return (unsigned short)((u + 0x7FFF + ((u >> 16) & 1)) >> 16);
}
__device__ inline float bf2f(unsigned short u) {
    union { unsigned u; float f; } x; x.u = (unsigned)u << 16; return x.f;
}

__device__ inline void storeC(float* C, size_t idx, float v) { C[idx] = v; }
__device__ inline void storeC(unsigned short* C, size_t idx, float v) { C[idx] = f2bf(v); }

// ---------------- pre-pass: weight transpose+convert, x convert ----------------
// W [K,N] fp32 -> Wt [N,K] bf16.  K,N multiples of 32.
__global__ __launch_bounds__(256) void transpose_bf16(const float* __restrict__ W,
                                                      unsigned short* __restrict__ Wt,
                                                      int K, int N) {
    __shared__ float t[32][33];
    int k0 = blockIdx.x * 32, n0 = blockIdx.y * 32;
    int c = threadIdx.x & 31, r8 = threadIdx.x >> 5;  // 8 rows per pass
    #pragma unroll
    for (int i = 0; i < 4; i++)
        t[r8 + i * 8][c] = W[(size_t)(k0 + r8 + i * 8) * N + n0 + c];
    __syncthreads();
    #pragma unroll
    for (int i = 0; i < 4; i++)
        Wt[(size_t)(n0 + r8 + i * 8) * K + k0 + c] = f2bf(t[c][r8 + i * 8]);
}

__global__ void cvt_bf16_v4(const float* __restrict__ in, unsigned short* __restrict__ out, int n4) {
    int i = blockIdx.x * blockDim.x + threadIdx.x;
    if (i < n4) {
        fx4 v = *(const fx4*)(in + (size_t)i * 4);
        us4 s;
        #pragma unroll
        for (int j = 0; j < 4; j++) s[j] = f2bf(v[j]);
        *(us4*)(out + (size_t)i * 4) = s;
    }
}

// ---------------- CSR construction ----------------
__global__ void count_init(int* cnt) {
    int n = blockIdx.x * blockDim.x + threadIdx.x;
    if (n < NN) cnt[n] = 1;  // self-loop
}

__global__ void count_edges(const int* dst, int* cnt) {
    int e = blockIdx.x * blockDim.x + threadIdx.x;
    if (e < EE) atomicAdd(&cnt[dst[e]], 1);
}

__global__ void scan_kernel(const int* cnt, int* indptr, int* cursor) {
    __shared__ int part[1024];
    int tid = threadIdx.x;
    const int CH = 20;
    int base = tid * CH;
    int sum = 0;
    for (int i = 0; i < CH; i++) {
        int idx = base + i;
        if (idx < NN) sum += cnt[idx];
    }
    part[tid] = sum;
    __syncthreads();
    for (int off = 1; off < 1024; off <<= 1) {
        int v = (tid >= off) ? part[tid - off] : 0;
        __syncthreads();
        part[tid] += v;
        __syncthreads();
    }
    int run = (tid == 0) ? 0 : part[tid - 1];
    for (int i = 0; i < CH; i++) {
        int idx = base + i;
        if (idx < NN) {
            indptr[idx] = run;
            cursor[idx] = run;
            run += cnt[idx];
        }
    }
    if (tid == 1023) indptr[NN] = run;
}

__global__ void scatter_self(int* cursor, int* esrc) {
    int n = blockIdx.x * blockDim.x + threadIdx.x;
    if (n < NN) {
        int pos = atomicAdd(&cursor[n], 1);
        esrc[pos] = n;
    }
}

__global__ void scatter_edges(const int* src, const int* dst, int* cursor, int* esrc) {
    int e = blockIdx.x * blockDim.x + threadIdx.x;
    if (e < EE) {
        int pos = atomicAdd(&cursor[dst[e]], 1);
        esrc[pos] = src[e];
    }
}

// ---------------- all-bf16 MFMA GEMM: C = A*Bt^T (+bias)(+relu) ----------------
// A [M,K] bf16 row-major lda; Bt [N,K] bf16 row-major ldbt; C [M,N] row-major.
// K%64==0, N%BN==0, M arbitrary. BM=128, BK=64, 4 waves; wave owns 32 x BN.
template <int BN, typename TC>
__global__ __launch_bounds__(256) void mfma_gemm(
    const unsigned short* __restrict__ A, int lda,
    const unsigned short* __restrict__ Bt, int ldbt,
    TC* __restrict__ C, int ldc,
    int M, int K,
    const float* __restrict__ bias, int relu)
{
    constexpr int BM = 128, BK = 64, LROW = 72;  // +8 bf16 pad -> 144B stride
    constexpr int NJ = BN / 16;
    __shared__ unsigned short Als[BM * LROW];
    __shared__ unsigned short Bls[BN * LROW];

    int tid = threadIdx.x;
    int lane = tid & 63, w = tid >> 6;
    int row0 = blockIdx.y * BM, col0 = blockIdx.x * BN;

    f32x4 acc[2][NJ];
    #pragma unroll
    for (int i = 0; i < 2; i++)
        #pragma unroll
        for (int j = 0; j < NJ; j++) acc[i][j] = (f32x4){0.f, 0.f, 0.f, 0.f};

    for (int k0 = 0; k0 < K; k0 += BK) {
        // stage A: 4 x us8 per thread, conflict-free writes
        #pragma unroll
        for (int i = 0; i < 4; i++) {
            int e = i * 2048 + tid * 8;
            int r = e >> 6, c = e & 63;
            int gr = row0 + r;
            us8 v = (us8){0, 0, 0, 0, 0, 0, 0, 0};
            if (gr < M) v = *(const us8*)(A + (size_t)gr * lda + k0 + c);
            *(us8*)&Als[r * LROW + c] = v;
        }
        // stage B: BN/32 x us8 per thread (Bt rows are contiguous in K)
        #pragma unroll
        for (int i = 0; i < BN / 32; i++) {
            int e = i * 2048 + tid * 8;
            int r = e >> 6, c = e & 63;
            *(us8*)&Bls[r * LROW + c] = *(const us8*)(Bt + (size_t)(col0 + r) * ldbt + k0 + c);
        }
        __syncthreads();
        #pragma unroll
        for (int kc = 0; kc < 2; kc++) {
            int koff = kc * 32 + (lane >> 4) * 8;
            bf16x8 af[2];
            #pragma unroll
            for (int i = 0; i < 2; i++)
                af[i] = *(bf16x8*)&Als[(w * 32 + i * 16 + (lane & 15)) * LROW + koff];
            bf16x8 bfr[NJ];
            #pragma unroll
            for (int j = 0; j < NJ; j++)
                bfr[j] = *(bf16x8*)&Bls[(j * 16 + (lane & 15)) * LROW + koff];
            #pragma unroll
            for (int i = 0; i < 2; i++)
                #pragma unroll
                for (int j = 0; j < NJ; j++)
                    acc[i][j] = __builtin_amdgcn_mfma_f32_16x16x32_bf16(af[i], bfr[j], acc[i][j], 0, 0, 0);
        }
        __syncthreads();
    }
    #pragma unroll
    for (int i = 0; i < 2; i++) {
        #pragma unroll
        for (int r = 0; r < 4; r++) {
            int row = row0 + w * 32 + i * 16 + ((lane >> 4) << 2) + r;
            if (row >= M) continue;
            #pragma unroll
            for (int j = 0; j < NJ; j++) {
                int col = col0 + j * 16 + (lane & 15);
                float v = acc[i][j][r] + (bias ? bias[col] : 0.f);
                if (relu) v = fmaxf(v, 0.f);
                storeC(C, (size_t)row * ldc + col, v);
            }
        }
    }
}

// ---------------- attention logits (bf16 h) ----------------
__global__ __launch_bounds__(256) void logits_kernel(
    const unsigned short* __restrict__ hbuf,
    const float* __restrict__ a_src, const float* __restrict__ a_dst,
    float* __restrict__ al, float* __restrict__ ar)
{
    int n = blockIdx.x;
    int h = threadIdx.x >> 6;
    int lane = threadIdx.x & 63;
    float v = bf2f(hbuf[(long)n * 256 + h * 64 + lane]);
    float ps = v * a_src[h * 64 + lane];
    float pd = v * a_dst[h * 64 + lane];
    #pragma unroll
    for (int off = 32; off; off >>= 1) {
        ps += __shfl_xor(ps, off);
        pd += __shfl_xor(pd, off);
    }
    if (lane == 0) {
        al[n * 4 + h] = ps;
        ar[n * 4 + h] = pd;
    }
}

// ---------------- GAT aggregation (bf16 h, bf16 out into z slice) ----------------
__global__ __launch_bounds__(256) void aggregate_kernel(
    const unsigned short* __restrict__ hbuf,
    const float* __restrict__ al, const float* __restrict__ ar,
    const int* __restrict__ indptr, const int* __restrict__ esrc,
    const float* __restrict__ bias,
    unsigned short* __restrict__ out, int ldo)
{
    int n = blockIdx.x;
    int h = threadIdx.x >> 6;
    int lane = threadIdx.x & 63;
    int beg = indptr[n], end = indptr[n + 1];
    float arn = ar[n * 4 + h];
    float mloc = -1e30f;
    for (int j = beg + lane; j < end; j += 64) {
        float e = al[esrc[j] * 4 + h] + arn;
        e = e > 0.f ? e : 0.2f * e;
        mloc = fmaxf(mloc, e);
    }
    #pragma unroll
    for (int off = 32; off; off >>= 1) mloc = fmaxf(mloc, __shfl_xor(mloc, off));
    float m = mloc;
    float ssum = 0.f, acc = 0.f;
    for (int j = beg; j < end; j++) {
        int s = esrc[j];
        float e = al[s * 4 + h] + arn;
        e = e > 0.f ? e : 0.2f * e;
        float ex = __expf(e - m);
        ssum += ex;
        acc += ex * bf2f(hbuf[(long)s * 256 + h * 64 + lane]);
    }
    float v = acc / (ssum + 1e-16f) + bias[h * 64 + lane];
    out[(long)n * ldo + h * 64 + lane] = f2bf(v);
}

// ---------------- output gathers ----------------
__global__ void gather_feats(const float* __restrict__ Bf, const float* __restrict__ Tf,
                             const int* __restrict__ voc, const int* __restrict__ batch,
                             float* __restrict__ out)
{
    int i = blockIdx.x * blockDim.x + threadIdx.x;
    if (i < NN * 128) {
        int n = i >> 7, c = i & 127;
        int t = voc[n];
        out[i] = Bf[(long)t * 128 + c];
        out[(long)NN * 128 + i] = Tf[(long)t * 128 + c];
    }
    if (i < NN) out[(long)NN * 128 * 2 + (long)NN * 64 + i] = (float)batch[i];
}

// ---------------- host-side orchestration ----------------
extern "C" void kernel_launch(void* const* d_in, const int* in_sizes, int n_in,
                              void* d_out, int out_size, void* d_ws, size_t ws_size,
                              hipStream_t stream) {
    const float* x     = (const float*)d_in[0];
    const int*   ei    = (const int*)d_in[1];
    const int*   batch = (const int*)d_in[2];
    const int*   voc   = (const int*)d_in[3];
    const float* Bf    = (const float*)d_in[4];
    const float* Tf    = (const float*)d_in[5];
    const float* W0    = (const float*)d_in[6];
    const float* as0   = (const float*)d_in[7];
    const float* ad0   = (const float*)d_in[8];
    const float* b0    = (const float*)d_in[9];
    const float* W1    = (const float*)d_in[10];
    const float* as1   = (const float*)d_in[11];
    const float* ad1   = (const float*)d_in[12];
    const float* b1    = (const float*)d_in[13];
    const float* W2    = (const float*)d_in[14];
    const float* as2   = (const float*)d_in[15];
    const float* ad2   = (const float*)d_in[16];
    const float* b2    = (const float*)d_in[17];
    const float* fcmax_w = (const float*)d_in[18];
    const float* fcmax_b = (const float*)d_in[19];
    const float* fc1_w = (const float*)d_in[20];
    const float* fc1_b = (const float*)d_in[21];
    const float* fc2_w = (const float*)d_in[22];
    const float* fc2_b = (const float*)d_in[23];
    const float* fc3_w = (const float*)d_in[24];
    const float* fc3_b = (const float*)d_in[25];
    float* out = (float*)d_out;

    char* p = (char*)d_ws;
    unsigned short* xb  = (unsigned short*)p; p += (size_t)NN * 128 * 2;
    unsigned short* hbuf= (unsigned short*)p; p += (size_t)NN * 256 * 2;
    unsigned short* z   = (unsigned short*)p; p += (size_t)NN * 1536 * 2;
    unsigned short* z1  = (unsigned short*)p; p += (size_t)NN * 512 * 2;
    unsigned short* h2  = (unsigned short*)p; p += (size_t)NN * 128 * 2;
    unsigned short* w0t = (unsigned short*)p; p += (size_t)128 * 256 * 2;
    unsigned short* w1t = (unsigned short*)p; p += (size_t)256 * 256 * 2;
    unsigned short* w2t = (unsigned short*)p; p += (size_t)256 * 256 * 2;
    unsigned short* wmt = (unsigned short*)p; p += (size_t)256 * 256 * 2;
    unsigned short* f1t = (unsigned short*)p; p += (size_t)1536 * 512 * 2;
    unsigned short* f2t = (unsigned short*)p; p += (size_t)512 * 128 * 2;
    unsigned short* f3t = (unsigned short*)p; p += (size_t)128 * 64 * 2;
    float* al   = (float*)p; p += (size_t)NN * 4 * 4;
    float* ar   = (float*)p; p += (size_t)NN * 4 * 4;
    int* cnt    = (int*)p;   p += (size_t)NN * 4;
    int* cursor = (int*)p;   p += (size_t)NN * 4;
    int* esrc   = (int*)p;   p += (size_t)ET * 4;
    int* indptr = (int*)p;   p += (size_t)(NN + 1) * 4;

    const int* e_src = ei;
    const int* e_dst = ei + EE;

    // ---- pre-pass: weights -> bf16 transposed, x -> bf16 ----
    transpose_bf16<<<dim3(4, 8),  256, 0, stream>>>(W0, w0t, 128, 256);
    transpose_bf16<<<dim3(8, 8),  256, 0, stream>>>(W1, w1t, 256, 256);
    transpose_bf16<<<dim3(8, 8),  256, 0, stream>>>(W2, w2t, 256, 256);
    transpose_bf16<<<dim3(8, 8),  256, 0, stream>>>(fcmax_w, wmt, 256, 256);
    transpose_bf16<<<dim3(48, 16),256, 0, stream>>>(fc1_w, f1t, 1536, 512);
    transpose_bf16<<<dim3(16, 4), 256, 0, stream>>>(fc2_w, f2t, 512, 128);
    transpose_bf16<<<dim3(4, 2),  256, 0, stream>>>(fc3_w, f3t, 128, 64);
    cvt_bf16_v4<<<(NN * 32 + 255) / 256, 256, 0, stream>>>(x, xb, NN * 32);

    // ---- CSR (dst-sorted incoming edges, incl. self-loops) ----
    count_init<<<(NN + 255) / 256, 256, 0, stream>>>(cnt);
    count_edges<<<(EE + 255) / 256, 256, 0, stream>>>(e_dst, cnt);
    scan_kernel<<<1, 1024, 0, stream>>>(cnt, indptr, cursor);
    scatter_self<<<(NN + 255) / 256, 256, 0, stream>>>(cursor, esrc);
    scatter_edges<<<(EE + 255) / 256, 256, 0, stream>>>(e_src, e_dst, cursor, esrc);

    // ---- independent output gathers ----
    gather_feats<<<(NN * 128 + 255) / 256, 256, 0, stream>>>(Bf, Tf, voc, batch, out);

    const int MB = (NN + 127) / 128;  // 157

    // ---- GAT layer 0 ----
    mfma_gemm<128, unsigned short><<<dim3(2, MB), 256, 0, stream>>>(xb, 128, w0t, 128, hbuf, 256, NN, 128, nullptr, 0);
    logits_kernel<<<NN, 256, 0, stream>>>(hbuf, as0, ad0, al, ar);
    aggregate_kernel<<<NN, 256, 0, stream>>>(hbuf, al, ar, indptr, esrc, b0, z + 0, 1536);
    mfma_gemm<128, unsigned short><<<dim3(2, MB), 256, 0, stream>>>(z + 0, 1536, wmt, 256, z + 256, 1536, NN, 256, fcmax_b, 1);

    // ---- GAT layer 1 ----
    mfma_gemm<128, unsigned short><<<dim3(2, MB), 256, 0, stream>>>(z + 256, 1536, w1t, 256, hbuf, 256, NN, 256, nullptr, 0);
    logits_kernel<<<NN, 256, 0, stream>>>(hbuf, as1, ad1, al, ar);
    aggregate_kernel<<<NN, 256, 0, stream>>>(hbuf, al, ar, indptr, esrc, b1, z + 512, 1536);
    mfma_gemm<128, unsigned short><<<dim3(2, MB), 256, 0, stream>>>(z + 512, 1536, wmt, 256, z + 768, 1536, NN, 256, fcmax_b, 1);

    // ---- GAT layer 2 ----
    mfma_gemm<128, unsigned short><<<dim3(2, MB), 256, 0, stream>>>(z + 768, 1536, w2t, 256, hbuf, 256, NN, 256, nullptr, 0);
    logits_kernel<<<NN, 256, 0, stream>>>(hbuf, as2, ad2, al, ar);
    aggregate_kernel<<<NN, 256, 0, stream>>>(hbuf, al, ar, indptr, esrc, b2, z + 1024, 1536);
    mfma_gemm<128, unsigned short><<<dim3(2, MB), 256, 0, stream>>>(z + 1024, 1536, wmt, 256, z + 1280, 1536, NN, 256, fcmax_b, 1);

    // ---- MLP head ----
    mfma_gemm<128, unsigned short><<<dim3(4, MB), 256, 0, stream>>>(z, 1536, f1t, 1536, z1, 512, NN, 1536, fc1_b, 1);
    mfma_gemm<128, unsigned short><<<dim3(1, MB), 256, 0, stream>>>(z1, 512, f2t, 512, h2, 128, NN, 512, fc2_b, 1);
    mfma_gemm<64, float><<<dim3(1, MB), 256, 0, stream>>>(h2, 128, f3t, 128, out + (size_t)2 * NN * 128, 64, NN, 128, fc3_b, 0);
}

// Round 5
// 617.481 us; speedup vs baseline: 1.9829x; 1.0608x over previous
//
#include <hip/hip_runtime.h>
#include <math.h>

#define NN 20000
#define NPAD 20096   // 157 * 128, so global_load_lds row staging never reads OOB
#define EE 320000
#define ET (EE + NN)

typedef __attribute__((ext_vector_type(8))) short bf16x8;
typedef __attribute__((ext_vector_type(4))) float f32x4;
typedef __attribute__((ext_vector_type(4))) unsigned short us4;
typedef __attribute__((ext_vector_type(8))) unsigned short us8;
typedef __attribute__((ext_vector_type(4))) float fx4;

__device__ inline unsigned short f2bf(float f) {
    union { float f; unsigned u; } x; x.f = f;
    unsigned u = x.u;
    return (unsigned short)((u + 0x7FFF + ((u >> 16) & 1)) >> 16);
}
__device__ inline float bf2f(unsigned short u) {
    union { unsigned u; float f; } x; x.u = (unsigned)u << 16; return x.f;
}

__device__ inline void storeC(float* C, size_t idx, float v) { C[idx] = v; }
__device__ inline void storeC(unsigned short* C, size_t idx, float v) { C[idx] = f2bf(v); }

// async 16B/lane global -> LDS (linear dest: wave base + lane*16)
__device__ inline void gload_lds16(const void* g, void* l) {
    __builtin_amdgcn_global_load_lds(
        (const __attribute__((address_space(1))) unsigned int*)g,
        (__attribute__((address_space(3))) unsigned int*)l, 16, 0, 0);
}

// ---------------- pre-pass: weight transpose+convert, x convert ----------------
__global__ __launch_bounds__(256) void transpose_bf16(const float* __restrict__ W,
                                                      unsigned short* __restrict__ Wt,
                                                      int K, int N) {
    __shared__ float t[32][33];
    int k0 = blockIdx.x * 32, n0 = blockIdx.y * 32;
    int c = threadIdx.x & 31, r8 = threadIdx.x >> 5;
    #pragma unroll
    for (int i = 0; i < 4; i++)
        t[r8 + i * 8][c] = W[(size_t)(k0 + r8 + i * 8) * N + n0 + c];
    __syncthreads();
    #pragma unroll
    for (int i = 0; i < 4; i++)
        Wt[(size_t)(n0 + r8 + i * 8) * K + k0 + c] = f2bf(t[c][r8 + i * 8]);
}

__global__ void cvt_bf16_v4(const float* __restrict__ in, unsigned short* __restrict__ out, int n4) {
    int i = blockIdx.x * blockDim.x + threadIdx.x;
    if (i < n4) {
        fx4 v = *(const fx4*)(in + (size_t)i * 4);
        us4 s;
        #pragma unroll
        for (int j = 0; j < 4; j++) s[j] = f2bf(v[j]);
        *(us4*)(out + (size_t)i * 4) = s;
    }
}

// ---------------- CSR construction ----------------
__global__ void count_init(int* cnt) {
    int n = blockIdx.x * blockDim.x + threadIdx.x;
    if (n < NN) cnt[n] = 1;  // self-loop
}

__global__ void count_edges(const int* dst, int* cnt) {
    int e = blockIdx.x * blockDim.x + threadIdx.x;
    if (e < EE) atomicAdd(&cnt[dst[e]], 1);
}

__global__ void scan_kernel(const int* cnt, int* indptr, int* cursor) {
    __shared__ int part[1024];
    int tid = threadIdx.x;
    const int CH = 20;
    int base = tid * CH;
    int sum = 0;
    for (int i = 0; i < CH; i++) {
        int idx = base + i;
        if (idx < NN) sum += cnt[idx];
    }
    part[tid] = sum;
    __syncthreads();
    for (int off = 1; off < 1024; off <<= 1) {
        int v = (tid >= off) ? part[tid - off] : 0;
        __syncthreads();
        part[tid] += v;
        __syncthreads();
    }
    int run = (tid == 0) ? 0 : part[tid - 1];
    for (int i = 0; i < CH; i++) {
        int idx = base + i;
        if (idx < NN) {
            indptr[idx] = run;
            cursor[idx] = run;
            run += cnt[idx];
        }
    }
    if (tid == 1023) indptr[NN] = run;
}

__global__ void scatter_self(int* cursor, int* esrc) {
    int n = blockIdx.x * blockDim.x + threadIdx.x;
    if (n < NN) {
        int pos = atomicAdd(&cursor[n], 1);
        esrc[pos] = n;
    }
}

__global__ void scatter_edges(const int* src, const int* dst, int* cursor, int* esrc) {
    int e = blockIdx.x * blockDim.x + threadIdx.x;
    if (e < EE) {
        int pos = atomicAdd(&cursor[dst[e]], 1);
        esrc[pos] = src[e];
    }
}

// ---------------- all-bf16 MFMA GEMM via global_load_lds ----------------
// C[M,N] = A[M,K] * Bt[N,K]^T (+bias)(+relu). K%64==0, N%BN==0.
// A rows must be readable up to ceil(M/128)*128 (padded ws buffers).
// BM=128, BK=64, 4 waves; wave owns 32 x BN. 1D grid, XCD-chunked swizzle.
template <int BN, typename TC>
__global__ __launch_bounds__(256) void mfma_gemm(
    const unsigned short* __restrict__ A, int lda,
    const unsigned short* __restrict__ Bt, int ldbt,
    TC* __restrict__ C, int ldc,
    int M, int K,
    const float* __restrict__ bias, int relu, int nwgx)
{
    constexpr int BM = 128, BK = 64;
    constexpr int NJ = BN / 16;
    constexpr int NCHB = BN / 8;          // B chunks (8 rows x 64 cols each)
    __shared__ unsigned short Als[BM * BK];
    __shared__ unsigned short Bls[BN * BK];

    // bijective XCD-chunked swizzle (m204): each XCD gets a contiguous id range
    int nwg = gridDim.x;
    int orig = blockIdx.x;
    int q = nwg >> 3, r = nwg & 7;
    int xcd = orig & 7, loc = orig >> 3;
    int swz = (xcd < r ? xcd * (q + 1) : r * (q + 1) + (xcd - r) * q) + loc;
    int bx = swz % nwgx, by = swz / nwgx;

    int tid = threadIdx.x;
    int lane = tid & 63, w = tid >> 6;
    int row0 = by * BM, col0 = bx * BN;

    f32x4 acc[2][NJ];
    #pragma unroll
    for (int i = 0; i < 2; i++)
        #pragma unroll
        for (int j = 0; j < NJ; j++) acc[i][j] = (f32x4){0.f, 0.f, 0.f, 0.f};

    int lr = lane >> 3;              // row within 8-row chunk
    int lc = (lane & 7) << 3;        // col (elements)

    for (int k0 = 0; k0 < K; k0 += BK) {
        // stage A: 16 chunks x 1KB, 4 global_load_lds per wave
        #pragma unroll
        for (int i = 0; i < 4; i++) {
            int ch = (w << 2) + i;
            int rrow = (ch << 3) + lr;
            gload_lds16(A + (size_t)(row0 + rrow) * lda + k0 + lc,
                        &Als[(ch << 9) + (lane << 3)]);
        }
        // stage B: NCHB chunks, NCHB/4 per wave
        #pragma unroll
        for (int i = 0; i < NCHB / 4; i++) {
            int ch = w * (NCHB / 4) + i;
            int rrow = (ch << 3) + lr;
            gload_lds16(Bt + (size_t)(col0 + rrow) * ldbt + k0 + lc,
                        &Bls[(ch << 9) + (lane << 3)]);
        }
        __syncthreads();   // drains vmcnt before barrier
        #pragma unroll
        for (int kc = 0; kc < 2; kc++) {
            int koff = kc * 32 + (lane >> 4) * 8;
            bf16x8 af[2];
            #pragma unroll
            for (int i = 0; i < 2; i++)
                af[i] = *(bf16x8*)&Als[(w * 32 + i * 16 + (lane & 15)) * BK + koff];
            bf16x8 bfr[NJ];
            #pragma unroll
            for (int j = 0; j < NJ; j++)
                bfr[j] = *(bf16x8*)&Bls[(j * 16 + (lane & 15)) * BK + koff];
            #pragma unroll
            for (int i = 0; i < 2; i++)
                #pragma unroll
                for (int j = 0; j < NJ; j++)
                    acc[i][j] = __builtin_amdgcn_mfma_f32_16x16x32_bf16(af[i], bfr[j], acc[i][j], 0, 0, 0);
        }
        __syncthreads();
    }
    #pragma unroll
    for (int i = 0; i < 2; i++) {
        #pragma unroll
        for (int rr = 0; rr < 4; rr++) {
            int row = row0 + w * 32 + i * 16 + ((lane >> 4) << 2) + rr;
            if (row >= M) continue;
            #pragma unroll
            for (int j = 0; j < NJ; j++) {
                int col = col0 + j * 16 + (lane & 15);
                float v = acc[i][j][rr] + (bias ? bias[col] : 0.f);
                if (relu) v = fmaxf(v, 0.f);
                storeC(C, (size_t)row * ldc + col, v);
            }
        }
    }
}

// ---------------- attention logits (bf16 h) ----------------
__global__ __launch_bounds__(256) void logits_kernel(
    const unsigned short* __restrict__ hbuf,
    const float* __restrict__ a_src, const float* __restrict__ a_dst,
    float* __restrict__ al, float* __restrict__ ar)
{
    int n = blockIdx.x;
    int h = threadIdx.x >> 6;
    int lane = threadIdx.x & 63;
    float v = bf2f(hbuf[(long)n * 256 + h * 64 + lane]);
    float ps = v * a_src[h * 64 + lane];
    float pd = v * a_dst[h * 64 + lane];
    #pragma unroll
    for (int off = 32; off; off >>= 1) {
        ps += __shfl_xor(ps, off);
        pd += __shfl_xor(pd, off);
    }
    if (lane == 0) {
        al[n * 4 + h] = ps;
        ar[n * 4 + h] = pd;
    }
}

// ---------------- GAT aggregation (bf16 h, bf16 out into z slice) ----------------
__global__ __launch_bounds__(256) void aggregate_kernel(
    const unsigned short* __restrict__ hbuf,
    const float* __restrict__ al, const float* __restrict__ ar,
    const int* __restrict__ indptr, const int* __restrict__ esrc,
    const float* __restrict__ bias,
    unsigned short* __restrict__ out, int ldo)
{
    int n = blockIdx.x;
    int h = threadIdx.x >> 6;
    int lane = threadIdx.x & 63;
    int beg = indptr[n], end = indptr[n + 1];
    float arn = ar[n * 4 + h];
    float mloc = -1e30f;
    for (int j = beg + lane; j < end; j += 64) {
        float e = al[esrc[j] * 4 + h] + arn;
        e = e > 0.f ? e : 0.2f * e;
        mloc = fmaxf(mloc, e);
    }
    #pragma unroll
    for (int off = 32; off; off >>= 1) mloc = fmaxf(mloc, __shfl_xor(mloc, off));
    float m = mloc;
    float ssum = 0.f, acc = 0.f;
    for (int j = beg; j < end; j++) {
        int s = esrc[j];
        float e = al[s * 4 + h] + arn;
        e = e > 0.f ? e : 0.2f * e;
        float ex = __expf(e - m);
        ssum += ex;
        acc += ex * bf2f(hbuf[(long)s * 256 + h * 64 + lane]);
    }
    float v = acc / (ssum + 1e-16f) + bias[h * 64 + lane];
    out[(long)n * ldo + h * 64 + lane] = f2bf(v);
}

// ---------------- output gathers ----------------
__global__ void gather_feats(const float* __restrict__ Bf, const float* __restrict__ Tf,
                             const int* __restrict__ voc, const int* __restrict__ batch,
                             float* __restrict__ out)
{
    int i = blockIdx.x * blockDim.x + threadIdx.x;
    if (i < NN * 128) {
        int n = i >> 7, c = i & 127;
        int t = voc[n];
        out[i] = Bf[(long)t * 128 + c];
        out[(long)NN * 128 + i] = Tf[(long)t * 128 + c];
    }
    if (i < NN) out[(long)NN * 128 * 2 + (long)NN * 64 + i] = (float)batch[i];
}

// ---------------- host-side orchestration ----------------
extern "C" void kernel_launch(void* const* d_in, const int* in_sizes, int n_in,
                              void* d_out, int out_size, void* d_ws, size_t ws_size,
                              hipStream_t stream) {
    const float* x     = (const float*)d_in[0];
    const int*   ei    = (const int*)d_in[1];
    const int*   batch = (const int*)d_in[2];
    const int*   voc   = (const int*)d_in[3];
    const float* Bf    = (const float*)d_in[4];
    const float* Tf    = (const float*)d_in[5];
    const float* W0    = (const float*)d_in[6];
    const float* as0   = (const float*)d_in[7];
    const float* ad0   = (const float*)d_in[8];
    const float* b0    = (const float*)d_in[9];
    const float* W1    = (const float*)d_in[10];
    const float* as1   = (const float*)d_in[11];
    const float* ad1   = (const float*)d_in[12];
    const float* b1    = (const float*)d_in[13];
    const float* W2    = (const float*)d_in[14];
    const float* as2   = (const float*)d_in[15];
    const float* ad2   = (const float*)d_in[16];
    const float* b2    = (const float*)d_in[17];
    const float* fcmax_w = (const float*)d_in[18];
    const float* fcmax_b = (const float*)d_in[19];
    const float* fc1_w = (const float*)d_in[20];
    const float* fc1_b = (const float*)d_in[21];
    const float* fc2_w = (const float*)d_in[22];
    const float* fc2_b = (const float*)d_in[23];
    const float* fc3_w = (const float*)d_in[24];
    const float* fc3_b = (const float*)d_in[25];
    float* out = (float*)d_out;

    char* p = (char*)d_ws;
    unsigned short* xb  = (unsigned short*)p; p += (size_t)NPAD * 128 * 2;
    unsigned short* hbuf= (unsigned short*)p; p += (size_t)NN * 256 * 2;
    unsigned short* z   = (unsigned short*)p; p += (size_t)NPAD * 1536 * 2;
    unsigned short* z1  = (unsigned short*)p; p += (size_t)NPAD * 512 * 2;
    unsigned short* h2  = (unsigned short*)p; p += (size_t)NPAD * 128 * 2;
    unsigned short* w0t = (unsigned short*)p; p += (size_t)128 * 256 * 2;
    unsigned short* w1t = (unsigned short*)p; p += (size_t)256 * 256 * 2;
    unsigned short* w2t = (unsigned short*)p; p += (size_t)256 * 256 * 2;
    unsigned short* wmt = (unsigned short*)p; p += (size_t)256 * 256 * 2;
    unsigned short* f1t = (unsigned short*)p; p += (size_t)1536 * 512 * 2;
    unsigned short* f2t = (unsigned short*)p; p += (size_t)512 * 128 * 2;
    unsigned short* f3t = (unsigned short*)p; p += (size_t)128 * 64 * 2;
    float* al   = (float*)p; p += (size_t)NN * 4 * 4;
    float* ar   = (float*)p; p += (size_t)NN * 4 * 4;
    int* cnt    = (int*)p;   p += (size_t)NN * 4;
    int* cursor = (int*)p;   p += (size_t)NN * 4;
    int* esrc   = (int*)p;   p += (size_t)ET * 4;
    int* indptr = (int*)p;   p += (size_t)(NN + 1) * 4;

    const int* e_src = ei;
    const int* e_dst = ei + EE;

    // ---- pre-pass: weights -> bf16 transposed, x -> bf16 ----
    transpose_bf16<<<dim3(4, 8),  256, 0, stream>>>(W0, w0t, 128, 256);
    transpose_bf16<<<dim3(8, 8),  256, 0, stream>>>(W1, w1t, 256, 256);
    transpose_bf16<<<dim3(8, 8),  256, 0, stream>>>(W2, w2t, 256, 256);
    transpose_bf16<<<dim3(8, 8),  256, 0, stream>>>(fcmax_w, wmt, 256, 256);
    transpose_bf16<<<dim3(48, 16),256, 0, stream>>>(fc1_w, f1t, 1536, 512);
    transpose_bf16<<<dim3(16, 4), 256, 0, stream>>>(fc2_w, f2t, 512, 128);
    transpose_bf16<<<dim3(4, 2),  256, 0, stream>>>(fc3_w, f3t, 128, 64);
    cvt_bf16_v4<<<(NN * 32 + 255) / 256, 256, 0, stream>>>(x, xb, NN * 32);

    // ---- CSR (dst-sorted incoming edges, incl. self-loops) ----
    count_init<<<(NN + 255) / 256, 256, 0, stream>>>(cnt);
    count_edges<<<(EE + 255) / 256, 256, 0, stream>>>(e_dst, cnt);
    scan_kernel<<<1, 1024, 0, stream>>>(cnt, indptr, cursor);
    scatter_self<<<(NN + 255) / 256, 256, 0, stream>>>(cursor, esrc);
    scatter_edges<<<(EE + 255) / 256, 256, 0, stream>>>(e_src, e_dst, cursor, esrc);

    // ---- independent output gathers ----
    gather_feats<<<(NN * 128 + 255) / 256, 256, 0, stream>>>(Bf, Tf, voc, batch, out);

    const int MB = (NPAD) / 128;  // 157

    // ---- GAT layer 0 ----
    mfma_gemm<128, unsigned short><<<2 * MB, 256, 0, stream>>>(xb, 128, w0t, 128, hbuf, 256, NN, 128, nullptr, 0, 2);
    logits_kernel<<<NN, 256, 0, stream>>>(hbuf, as0, ad0, al, ar);
    aggregate_kernel<<<NN, 256, 0, stream>>>(hbuf, al, ar, indptr, esrc, b0, z + 0, 1536);
    mfma_gemm<128, unsigned short><<<2 * MB, 256, 0, stream>>>(z + 0, 1536, wmt, 256, z + 256, 1536, NN, 256, fcmax_b, 1, 2);

    // ---- GAT layer 1 ----
    mfma_gemm<128, unsigned short><<<2 * MB, 256, 0, stream>>>(z + 256, 1536, w1t, 256, hbuf, 256, NN, 256, nullptr, 0, 2);
    logits_kernel<<<NN, 256, 0, stream>>>(hbuf, as1, ad1, al, ar);
    aggregate_kernel<<<NN, 256, 0, stream>>>(hbuf, al, ar, indptr, esrc, b1, z + 512, 1536);
    mfma_gemm<128, unsigned short><<<2 * MB, 256, 0, stream>>>(z + 512, 1536, wmt, 256, z + 768, 1536, NN, 256, fcmax_b, 1, 2);

    // ---- GAT layer 2 ----
    mfma_gemm<128, unsigned short><<<2 * MB, 256, 0, stream>>>(z + 768, 1536, w2t, 256, hbuf, 256, NN, 256, nullptr, 0, 2);
    logits_kernel<<<NN, 256, 0, stream>>>(hbuf, as2, ad2, al, ar);
    aggregate_kernel<<<NN, 256, 0, stream>>>(hbuf, al, ar, indptr, esrc, b2, z + 1024, 1536);
    mfma_gemm<128, unsigned short><<<2 * MB, 256, 0, stream>>>(z + 1024, 1536, wmt, 256, z + 1280, 1536, NN, 256, fcmax_b, 1, 2);

    // ---- MLP head ----
    mfma_gemm<128, unsigned short><<<4 * MB, 256, 0, stream>>>(z, 1536, f1t, 1536, z1, 512, NN, 1536, fc1_b, 1, 4);
    mfma_gemm<128, unsigned short><<<1 * MB, 256, 0, stream>>>(z1, 512, f2t, 512, h2, 128, NN, 512, fc2_b, 1, 1);
    mfma_gemm<64, float><<<1 * MB, 256, 0, stream>>>(h2, 128, f3t, 128, out + (size_t)2 * NN * 128, 64, NN, 128, fc3_b, 0, 1);
}

// Round 6
// 549.634 us; speedup vs baseline: 2.2277x; 1.1234x over previous
//
#include <hip/hip_runtime.h>
#include <math.h>

#define NN 20000
#define NPAD 20096   // 157 * 128: staging reads never go OOB
#define EE 320000
#define ET (EE + NN)

typedef __attribute__((ext_vector_type(8))) short bf16x8;
typedef __attribute__((ext_vector_type(4))) float f32x4;
typedef __attribute__((ext_vector_type(4))) unsigned short us4;
typedef __attribute__((ext_vector_type(8))) unsigned short us8;
typedef __attribute__((ext_vector_type(4))) float fx4;

__device__ inline unsigned short f2bf(float f) {
    union { float f; unsigned u; } x; x.f = f;
    unsigned u = x.u;
    return (unsigned short)((u + 0x7FFF + ((u >> 16) & 1)) >> 16);
}
__device__ inline float bf2f(unsigned short u) {
    union { unsigned u; float f; } x; x.u = (unsigned)u << 16; return x.f;
}

__device__ inline void storeC(float* C, size_t idx, float v) { C[idx] = v; }
__device__ inline void storeC(unsigned short* C, size_t idx, float v) { C[idx] = f2bf(v); }

// async 16B/lane global -> LDS (linear dest: wave base + lane*16)
__device__ inline void gload_lds16(const void* g, void* l) {
    __builtin_amdgcn_global_load_lds(
        (const __attribute__((address_space(1))) unsigned int*)g,
        (__attribute__((address_space(3))) unsigned int*)l, 16, 0, 0);
}

// ---------------- pre-pass: weight transpose+convert, x convert ----------------
__global__ __launch_bounds__(256) void transpose_bf16(const float* __restrict__ W,
                                                      unsigned short* __restrict__ Wt,
                                                      int K, int N) {
    __shared__ float t[32][33];
    int k0 = blockIdx.x * 32, n0 = blockIdx.y * 32;
    int c = threadIdx.x & 31, r8 = threadIdx.x >> 5;
    #pragma unroll
    for (int i = 0; i < 4; i++)
        t[r8 + i * 8][c] = W[(size_t)(k0 + r8 + i * 8) * N + n0 + c];
    __syncthreads();
    #pragma unroll
    for (int i = 0; i < 4; i++)
        Wt[(size_t)(n0 + r8 + i * 8) * K + k0 + c] = f2bf(t[c][r8 + i * 8]);
}

__global__ void cvt_bf16_v4(const float* __restrict__ in, unsigned short* __restrict__ out, int n4) {
    int i = blockIdx.x * blockDim.x + threadIdx.x;
    if (i < n4) {
        fx4 v = *(const fx4*)(in + (size_t)i * 4);
        us4 s;
        #pragma unroll
        for (int j = 0; j < 4; j++) s[j] = f2bf(v[j]);
        *(us4*)(out + (size_t)i * 4) = s;
    }
}

// ---------------- CSR construction ----------------
__global__ void count_init(int* cnt) {
    int n = blockIdx.x * blockDim.x + threadIdx.x;
    if (n < NN) cnt[n] = 1;  // self-loop
}

__global__ void count_edges(const int* dst, int* cnt) {
    int e = blockIdx.x * blockDim.x + threadIdx.x;
    if (e < EE) atomicAdd(&cnt[dst[e]], 1);
}

__global__ void scan_kernel(const int* cnt, int* indptr, int* cursor) {
    __shared__ int part[1024];
    int tid = threadIdx.x;
    const int CH = 20;
    int base = tid * CH;
    int sum = 0;
    for (int i = 0; i < CH; i++) {
        int idx = base + i;
        if (idx < NN) sum += cnt[idx];
    }
    part[tid] = sum;
    __syncthreads();
    for (int off = 1; off < 1024; off <<= 1) {
        int v = (tid >= off) ? part[tid - off] : 0;
        __syncthreads();
        part[tid] += v;
        __syncthreads();
    }
    int run = (tid == 0) ? 0 : part[tid - 1];
    for (int i = 0; i < CH; i++) {
        int idx = base + i;
        if (idx < NN) {
            indptr[idx] = run;
            cursor[idx] = run;
            run += cnt[idx];
        }
    }
    if (tid == 1023) indptr[NN] = run;
}

__global__ void scatter_self(int* cursor, int* esrc) {
    int n = blockIdx.x * blockDim.x + threadIdx.x;
    if (n < NN) {
        int pos = atomicAdd(&cursor[n], 1);
        esrc[pos] = n;
    }
}

__global__ void scatter_edges(const int* src, const int* dst, int* cursor, int* esrc) {
    int e = blockIdx.x * blockDim.x + threadIdx.x;
    if (e < EE) {
        int pos = atomicAdd(&cursor[dst[e]], 1);
        esrc[pos] = src[e];
    }
}

// ---------------- all-bf16 MFMA GEMM, dbuf prefetch + swizzled LDS ----------------
// C[M,N] = A[M,K] * Bt[N,K]^T (+bias)(+relu). K%64==0, N%BN==0, K>=128.
// A/Bt rows readable up to ceil(M/128)*128 (padded ws buffers).
// BM=128, BK=64, 4 waves; wave owns 32 x BN. 1D grid, XCD-chunked swizzle.
template <int BN, typename TC>
__global__ __launch_bounds__(256) void mfma_gemm(
    const unsigned short* __restrict__ A, int lda,
    const unsigned short* __restrict__ Bt, int ldbt,
    TC* __restrict__ C, int ldc,
    int M, int K,
    const float* __restrict__ bias, int relu, int nwgx)
{
    constexpr int BM = 128, BK = 64;
    constexpr int NJ = BN / 16;
    constexpr int NCHB = BN / 8;          // B chunks (8 rows x 64 cols)
    __shared__ unsigned short Als[2][BM * BK];
    __shared__ unsigned short Bls[2][BN * BK];

    // bijective XCD-chunked swizzle (m204)
    int nwg = gridDim.x;
    int orig = blockIdx.x;
    int q = nwg >> 3, r = nwg & 7;
    int xcd = orig & 7, loc = orig >> 3;
    int swz = (xcd < r ? xcd * (q + 1) : r * (q + 1) + (xcd - r) * q) + loc;
    int bx = swz % nwgx, by = swz / nwgx;

    int tid = threadIdx.x;
    int lane = tid & 63, w = tid >> 6;
    int row0 = by * BM, col0 = bx * BN;

    int lr = lane >> 3;                 // row within 8-row chunk
    int scol = ((lane & 7) ^ lr) << 3;  // inverse-swizzled source element offset

    f32x4 acc[2][NJ];
    #pragma unroll
    for (int i = 0; i < 2; i++)
        #pragma unroll
        for (int j = 0; j < NJ; j++) acc[i][j] = (f32x4){0.f, 0.f, 0.f, 0.f};

    auto stage = [&](int buf, int k0) {
        #pragma unroll
        for (int i = 0; i < 4; i++) {
            int ch = (w << 2) + i;
            gload_lds16(A + (size_t)(row0 + (ch << 3) + lr) * lda + k0 + scol,
                        &Als[buf][(ch << 9) + (lane << 3)]);
        }
        #pragma unroll
        for (int i = 0; i < NCHB / 4; i++) {
            int ch = w * (NCHB / 4) + i;
            gload_lds16(Bt + (size_t)(col0 + (ch << 3) + lr) * ldbt + k0 + scol,
                        &Bls[buf][(ch << 9) + (lane << 3)]);
        }
    };

    auto compute = [&](int buf) {
        #pragma unroll
        for (int kc = 0; kc < 2; kc++) {
            int ks = (kc << 2) + (lane >> 4);   // 16B-slot index within row
            bf16x8 af[2];
            #pragma unroll
            for (int i = 0; i < 2; i++) {
                int rr = (w << 5) + (i << 4) + (lane & 15);
                af[i] = *(bf16x8*)&Als[buf][(rr << 6) + ((ks ^ (rr & 7)) << 3)];
            }
            bf16x8 bfr[NJ];
            #pragma unroll
            for (int j = 0; j < NJ; j++) {
                int rr = (j << 4) + (lane & 15);
                bfr[j] = *(bf16x8*)&Bls[buf][(rr << 6) + ((ks ^ (rr & 7)) << 3)];
            }
            #pragma unroll
            for (int i = 0; i < 2; i++)
                #pragma unroll
                for (int j = 0; j < NJ; j++)
                    acc[i][j] = __builtin_amdgcn_mfma_f32_16x16x32_bf16(af[i], bfr[j], acc[i][j], 0, 0, 0);
        }
    };

    // prologue
    stage(0, 0);
    asm volatile("s_waitcnt vmcnt(0)" ::: "memory");
    __builtin_amdgcn_s_barrier();
    int NT = K >> 6, cur = 0;
    for (int t = 0; t < NT - 1; ++t) {
        stage(cur ^ 1, (t + 1) << 6);   // prefetch next tile (overlaps compute)
        compute(cur);
        asm volatile("s_waitcnt vmcnt(0)" ::: "memory");
        __builtin_amdgcn_s_barrier();
        cur ^= 1;
    }
    compute(cur);

    #pragma unroll
    for (int i = 0; i < 2; i++) {
        #pragma unroll
        for (int rr = 0; rr < 4; rr++) {
            int row = row0 + w * 32 + i * 16 + ((lane >> 4) << 2) + rr;
            if (row >= M) continue;
            #pragma unroll
            for (int j = 0; j < NJ; j++) {
                int col = col0 + j * 16 + (lane & 15);
                float v = acc[i][j][rr] + (bias ? bias[col] : 0.f);
                if (relu) v = fmaxf(v, 0.f);
                storeC(C, (size_t)row * ldc + col, v);
            }
        }
    }
}

// ---------------- attention logits (bf16 h) ----------------
__global__ __launch_bounds__(256) void logits_kernel(
    const unsigned short* __restrict__ hbuf,
    const float* __restrict__ a_src, const float* __restrict__ a_dst,
    float* __restrict__ al, float* __restrict__ ar)
{
    int n = blockIdx.x;
    int h = threadIdx.x >> 6;
    int lane = threadIdx.x & 63;
    float v = bf2f(hbuf[(long)n * 256 + h * 64 + lane]);
    float ps = v * a_src[h * 64 + lane];
    float pd = v * a_dst[h * 64 + lane];
    #pragma unroll
    for (int off = 32; off; off >>= 1) {
        ps += __shfl_xor(ps, off);
        pd += __shfl_xor(pd, off);
    }
    if (lane == 0) {
        al[n * 4 + h] = ps;
        ar[n * 4 + h] = pd;
    }
}

// ---------------- GAT aggregation (bf16 h, bf16 out into z slice) ----------------
__global__ __launch_bounds__(256) void aggregate_kernel(
    const unsigned short* __restrict__ hbuf,
    const float* __restrict__ al, const float* __restrict__ ar,
    const int* __restrict__ indptr, const int* __restrict__ esrc,
    const float* __restrict__ bias,
    unsigned short* __restrict__ out, int ldo)
{
    int n = blockIdx.x;
    int h = threadIdx.x >> 6;
    int lane = threadIdx.x & 63;
    int beg = indptr[n], end = indptr[n + 1];
    float arn = ar[n * 4 + h];
    float mloc = -1e30f;
    for (int j = beg + lane; j < end; j += 64) {
        float e = al[esrc[j] * 4 + h] + arn;
        e = e > 0.f ? e : 0.2f * e;
        mloc = fmaxf(mloc, e);
    }
    #pragma unroll
    for (int off = 32; off; off >>= 1) mloc = fmaxf(mloc, __shfl_xor(mloc, off));
    float m = mloc;
    float ssum = 0.f, acc = 0.f;
    for (int j = beg; j < end; j++) {
        int s = esrc[j];
        float e = al[s * 4 + h] + arn;
        e = e > 0.f ? e : 0.2f * e;
        float ex = __expf(e - m);
        ssum += ex;
        acc += ex * bf2f(hbuf[(long)s * 256 + h * 64 + lane]);
    }
    float v = acc / (ssum + 1e-16f) + bias[h * 64 + lane];
    out[(long)n * ldo + h * 64 + lane] = f2bf(v);
}

// ---------------- output gathers ----------------
__global__ void gather_feats(const float* __restrict__ Bf, const float* __restrict__ Tf,
                             const int* __restrict__ voc, const int* __restrict__ batch,
                             float* __restrict__ out)
{
    int i = blockIdx.x * blockDim.x + threadIdx.x;
    if (i < NN * 128) {
        int n = i >> 7, c = i & 127;
        int t = voc[n];
        out[i] = Bf[(long)t * 128 + c];
        out[(long)NN * 128 + i] = Tf[(long)t * 128 + c];
    }
    if (i < NN) out[(long)NN * 128 * 2 + (long)NN * 64 + i] = (float)batch[i];
}

// ---------------- host-side orchestration ----------------
extern "C" void kernel_launch(void* const* d_in, const int* in_sizes, int n_in,
                              void* d_out, int out_size, void* d_ws, size_t ws_size,
                              hipStream_t stream) {
    const float* x     = (const float*)d_in[0];
    const int*   ei    = (const int*)d_in[1];
    const int*   batch = (const int*)d_in[2];
    const int*   voc   = (const int*)d_in[3];
    const float* Bf    = (const float*)d_in[4];
    const float* Tf    = (const float*)d_in[5];
    const float* W0    = (const float*)d_in[6];
    const float* as0   = (const float*)d_in[7];
    const float* ad0   = (const float*)d_in[8];
    const float* b0    = (const float*)d_in[9];
    const float* W1    = (const float*)d_in[10];
    const float* as1   = (const float*)d_in[11];
    const float* ad1   = (const float*)d_in[12];
    const float* b1    = (const float*)d_in[13];
    const float* W2    = (const float*)d_in[14];
    const float* as2   = (const float*)d_in[15];
    const float* ad2   = (const float*)d_in[16];
    const float* b2    = (const float*)d_in[17];
    const float* fcmax_w = (const float*)d_in[18];
    const float* fcmax_b = (const float*)d_in[19];
    const float* fc1_w = (const float*)d_in[20];
    const float* fc1_b = (const float*)d_in[21];
    const float* fc2_w = (const float*)d_in[22];
    const float* fc2_b = (const float*)d_in[23];
    const float* fc3_w = (const float*)d_in[24];
    const float* fc3_b = (const float*)d_in[25];
    float* out = (float*)d_out;

    char* p = (char*)d_ws;
    unsigned short* xb  = (unsigned short*)p; p += (size_t)NPAD * 128 * 2;
    unsigned short* hbuf= (unsigned short*)p; p += (size_t)NN * 256 * 2;
    unsigned short* z   = (unsigned short*)p; p += (size_t)NPAD * 1536 * 2;
    unsigned short* z1  = (unsigned short*)p; p += (size_t)NPAD * 512 * 2;
    unsigned short* h2  = (unsigned short*)p; p += (size_t)NPAD * 128 * 2;
    unsigned short* w0t = (unsigned short*)p; p += (size_t)128 * 256 * 2;
    unsigned short* w1t = (unsigned short*)p; p += (size_t)256 * 256 * 2;
    unsigned short* w2t = (unsigned short*)p; p += (size_t)256 * 256 * 2;
    unsigned short* wmt = (unsigned short*)p; p += (size_t)256 * 256 * 2;
    unsigned short* f1t = (unsigned short*)p; p += (size_t)1536 * 512 * 2;
    unsigned short* f2t = (unsigned short*)p; p += (size_t)512 * 128 * 2;
    unsigned short* f3t = (unsigned short*)p; p += (size_t)128 * 64 * 2;
    float* al   = (float*)p; p += (size_t)NN * 4 * 4;
    float* ar   = (float*)p; p += (size_t)NN * 4 * 4;
    int* cnt    = (int*)p;   p += (size_t)NN * 4;
    int* cursor = (int*)p;   p += (size_t)NN * 4;
    int* esrc   = (int*)p;   p += (size_t)ET * 4;
    int* indptr = (int*)p;   p += (size_t)(NN + 1) * 4;

    const int* e_src = ei;
    const int* e_dst = ei + EE;

    // ---- pre-pass: weights -> bf16 transposed, x -> bf16 ----
    transpose_bf16<<<dim3(4, 8),  256, 0, stream>>>(W0, w0t, 128, 256);
    transpose_bf16<<<dim3(8, 8),  256, 0, stream>>>(W1, w1t, 256, 256);
    transpose_bf16<<<dim3(8, 8),  256, 0, stream>>>(W2, w2t, 256, 256);
    transpose_bf16<<<dim3(8, 8),  256, 0, stream>>>(fcmax_w, wmt, 256, 256);
    transpose_bf16<<<dim3(48, 16),256, 0, stream>>>(fc1_w, f1t, 1536, 512);
    transpose_bf16<<<dim3(16, 4), 256, 0, stream>>>(fc2_w, f2t, 512, 128);
    transpose_bf16<<<dim3(4, 2),  256, 0, stream>>>(fc3_w, f3t, 128, 64);
    cvt_bf16_v4<<<(NN * 32 + 255) / 256, 256, 0, stream>>>(x, xb, NN * 32);

    // ---- CSR (dst-sorted incoming edges, incl. self-loops) ----
    count_init<<<(NN + 255) / 256, 256, 0, stream>>>(cnt);
    count_edges<<<(EE + 255) / 256, 256, 0, stream>>>(e_dst, cnt);
    scan_kernel<<<1, 1024, 0, stream>>>(cnt, indptr, cursor);
    scatter_self<<<(NN + 255) / 256, 256, 0, stream>>>(cursor, esrc);
    scatter_edges<<<(EE + 255) / 256, 256, 0, stream>>>(e_src, e_dst, cursor, esrc);

    // ---- independent output gathers ----
    gather_feats<<<(NN * 128 + 255) / 256, 256, 0, stream>>>(Bf, Tf, voc, batch, out);

    const int MB = NPAD / 128;  // 157

    // ---- GAT layer 0 ----
    mfma_gemm<64, unsigned short><<<4 * MB, 256, 0, stream>>>(xb, 128, w0t, 128, hbuf, 256, NN, 128, nullptr, 0, 4);
    logits_kernel<<<NN, 256, 0, stream>>>(hbuf, as0, ad0, al, ar);
    aggregate_kernel<<<NN, 256, 0, stream>>>(hbuf, al, ar, indptr, esrc, b0, z + 0, 1536);
    mfma_gemm<64, unsigned short><<<4 * MB, 256, 0, stream>>>(z + 0, 1536, wmt, 256, z + 256, 1536, NN, 256, fcmax_b, 1, 4);

    // ---- GAT layer 1 ----
    mfma_gemm<64, unsigned short><<<4 * MB, 256, 0, stream>>>(z + 256, 1536, w1t, 256, hbuf, 256, NN, 256, nullptr, 0, 4);
    logits_kernel<<<NN, 256, 0, stream>>>(hbuf, as1, ad1, al, ar);
    aggregate_kernel<<<NN, 256, 0, stream>>>(hbuf, al, ar, indptr, esrc, b1, z + 512, 1536);
    mfma_gemm<64, unsigned short><<<4 * MB, 256, 0, stream>>>(z + 512, 1536, wmt, 256, z + 768, 1536, NN, 256, fcmax_b, 1, 4);

    // ---- GAT layer 2 ----
    mfma_gemm<64, unsigned short><<<4 * MB, 256, 0, stream>>>(z + 768, 1536, w2t, 256, hbuf, 256, NN, 256, nullptr, 0, 4);
    logits_kernel<<<NN, 256, 0, stream>>>(hbuf, as2, ad2, al, ar);
    aggregate_kernel<<<NN, 256, 0, stream>>>(hbuf, al, ar, indptr, esrc, b2, z + 1024, 1536);
    mfma_gemm<64, unsigned short><<<4 * MB, 256, 0, stream>>>(z + 1024, 1536, wmt, 256, z + 1280, 1536, NN, 256, fcmax_b, 1, 4);

    // ---- MLP head ----
    mfma_gemm<128, unsigned short><<<4 * MB, 256, 0, stream>>>(z, 1536, f1t, 1536, z1, 512, NN, 1536, fc1_b, 1, 4);
    mfma_gemm<64, unsigned short><<<2 * MB, 256, 0, stream>>>(z1, 512, f2t, 512, h2, 128, NN, 512, fc2_b, 1, 2);
    mfma_gemm<64, float><<<1 * MB, 256, 0, stream>>>(h2, 128, f3t, 128, out + (size_t)2 * NN * 128, 64, NN, 128, fc3_b, 0, 1);
}

// Round 7
// 368.776 us; speedup vs baseline: 3.3202x; 1.4904x over previous
//
#include <hip/hip_runtime.h>
#include <math.h>

#define NN 20000
#define NPAD 20096   // 157 * 128: staging reads never go OOB
#define EE 320000
#define ET (EE + NN)

typedef __attribute__((ext_vector_type(8))) short bf16x8;
typedef __attribute__((ext_vector_type(4))) float f32x4;
typedef __attribute__((ext_vector_type(4))) unsigned short us4;
typedef __attribute__((ext_vector_type(8))) unsigned short us8;
typedef __attribute__((ext_vector_type(4))) float fx4;

__device__ inline unsigned short f2bf(float f) {
    union { float f; unsigned u; } x; x.f = f;
    unsigned u = x.u;
    return (unsigned short)((u + 0x7FFF + ((u >> 16) & 1)) >> 16);
}
__device__ inline float bf2f(unsigned short u) {
    union { unsigned u; float f; } x; x.u = (unsigned)u << 16; return x.f;
}

__device__ inline void storeC(float* C, size_t idx, float v) { C[idx] = v; }
__device__ inline void storeC(unsigned short* C, size_t idx, float v) { C[idx] = f2bf(v); }

// async 16B/lane global -> LDS (linear dest: wave base + lane*16)
__device__ inline void gload_lds16(const void* g, void* l) {
    __builtin_amdgcn_global_load_lds(
        (const __attribute__((address_space(1))) unsigned int*)g,
        (__attribute__((address_space(3))) unsigned int*)l, 16, 0, 0);
}

// ---------------- pre-pass: weight transpose+convert, x convert ----------------
__global__ __launch_bounds__(256) void transpose_bf16(const float* __restrict__ W,
                                                      unsigned short* __restrict__ Wt,
                                                      int K, int N) {
    __shared__ float t[32][33];
    int k0 = blockIdx.x * 32, n0 = blockIdx.y * 32;
    int c = threadIdx.x & 31, r8 = threadIdx.x >> 5;
    #pragma unroll
    for (int i = 0; i < 4; i++)
        t[r8 + i * 8][c] = W[(size_t)(k0 + r8 + i * 8) * N + n0 + c];
    __syncthreads();
    #pragma unroll
    for (int i = 0; i < 4; i++)
        Wt[(size_t)(n0 + r8 + i * 8) * K + k0 + c] = f2bf(t[c][r8 + i * 8]);
}

__global__ void cvt_bf16_v4(const float* __restrict__ in, unsigned short* __restrict__ out, int n4) {
    int i = blockIdx.x * blockDim.x + threadIdx.x;
    if (i < n4) {
        fx4 v = *(const fx4*)(in + (size_t)i * 4);
        us4 s;
        #pragma unroll
        for (int j = 0; j < 4; j++) s[j] = f2bf(v[j]);
        *(us4*)(out + (size_t)i * 4) = s;
    }
}

// ---------------- CSR construction ----------------
__global__ void count_init(int* cnt) {
    int n = blockIdx.x * blockDim.x + threadIdx.x;
    if (n < NN) cnt[n] = 1;  // self-loop
}

__global__ void count_edges(const int* dst, int* cnt) {
    int e = blockIdx.x * blockDim.x + threadIdx.x;
    if (e < EE) atomicAdd(&cnt[dst[e]], 1);
}

__global__ void scan_kernel(const int* cnt, int* indptr, int* cursor) {
    __shared__ int part[1024];
    int tid = threadIdx.x;
    const int CH = 20;
    int base = tid * CH;
    int sum = 0;
    for (int i = 0; i < CH; i++) {
        int idx = base + i;
        if (idx < NN) sum += cnt[idx];
    }
    part[tid] = sum;
    __syncthreads();
    for (int off = 1; off < 1024; off <<= 1) {
        int v = (tid >= off) ? part[tid - off] : 0;
        __syncthreads();
        part[tid] += v;
        __syncthreads();
    }
    int run = (tid == 0) ? 0 : part[tid - 1];
    for (int i = 0; i < CH; i++) {
        int idx = base + i;
        if (idx < NN) {
            indptr[idx] = run;
            cursor[idx] = run;
            run += cnt[idx];
        }
    }
    if (tid == 1023) indptr[NN] = run;
}

__global__ void scatter_self(int* cursor, int* esrc) {
    int n = blockIdx.x * blockDim.x + threadIdx.x;
    if (n < NN) {
        int pos = atomicAdd(&cursor[n], 1);
        esrc[pos] = n;
    }
}

__global__ void scatter_edges(const int* src, const int* dst, int* cursor, int* esrc) {
    int e = blockIdx.x * blockDim.x + threadIdx.x;
    if (e < EE) {
        int pos = atomicAdd(&cursor[dst[e]], 1);
        esrc[pos] = src[e];
    }
}

// ---------------- all-bf16 MFMA GEMM, dbuf prefetch + swizzled LDS ----------------
template <int BN, typename TC>
__global__ __launch_bounds__(256) void mfma_gemm(
    const unsigned short* __restrict__ A, int lda,
    const unsigned short* __restrict__ Bt, int ldbt,
    TC* __restrict__ C, int ldc,
    int M, int K,
    const float* __restrict__ bias, int relu, int nwgx)
{
    constexpr int BM = 128, BK = 64;
    constexpr int NJ = BN / 16;
    constexpr int NCHB = BN / 8;
    __shared__ unsigned short Als[2][BM * BK];
    __shared__ unsigned short Bls[2][BN * BK];

    int nwg = gridDim.x;
    int orig = blockIdx.x;
    int q = nwg >> 3, r = nwg & 7;
    int xcd = orig & 7, loc = orig >> 3;
    int swz = (xcd < r ? xcd * (q + 1) : r * (q + 1) + (xcd - r) * q) + loc;
    int bx = swz % nwgx, by = swz / nwgx;

    int tid = threadIdx.x;
    int lane = tid & 63, w = tid >> 6;
    int row0 = by * BM, col0 = bx * BN;

    int lr = lane >> 3;
    int scol = ((lane & 7) ^ lr) << 3;

    f32x4 acc[2][NJ];
    #pragma unroll
    for (int i = 0; i < 2; i++)
        #pragma unroll
        for (int j = 0; j < NJ; j++) acc[i][j] = (f32x4){0.f, 0.f, 0.f, 0.f};

    auto stage = [&](int buf, int k0) {
        #pragma unroll
        for (int i = 0; i < 4; i++) {
            int ch = (w << 2) + i;
            gload_lds16(A + (size_t)(row0 + (ch << 3) + lr) * lda + k0 + scol,
                        &Als[buf][(ch << 9) + (lane << 3)]);
        }
        #pragma unroll
        for (int i = 0; i < NCHB / 4; i++) {
            int ch = w * (NCHB / 4) + i;
            gload_lds16(Bt + (size_t)(col0 + (ch << 3) + lr) * ldbt + k0 + scol,
                        &Bls[buf][(ch << 9) + (lane << 3)]);
        }
    };

    auto compute = [&](int buf) {
        #pragma unroll
        for (int kc = 0; kc < 2; kc++) {
            int ks = (kc << 2) + (lane >> 4);
            bf16x8 af[2];
            #pragma unroll
            for (int i = 0; i < 2; i++) {
                int rr = (w << 5) + (i << 4) + (lane & 15);
                af[i] = *(bf16x8*)&Als[buf][(rr << 6) + ((ks ^ (rr & 7)) << 3)];
            }
            bf16x8 bfr[NJ];
            #pragma unroll
            for (int j = 0; j < NJ; j++) {
                int rr = (j << 4) + (lane & 15);
                bfr[j] = *(bf16x8*)&Bls[buf][(rr << 6) + ((ks ^ (rr & 7)) << 3)];
            }
            #pragma unroll
            for (int i = 0; i < 2; i++)
                #pragma unroll
                for (int j = 0; j < NJ; j++)
                    acc[i][j] = __builtin_amdgcn_mfma_f32_16x16x32_bf16(af[i], bfr[j], acc[i][j], 0, 0, 0);
        }
    };

    stage(0, 0);
    asm volatile("s_waitcnt vmcnt(0)" ::: "memory");
    __builtin_amdgcn_s_barrier();
    int NT = K >> 6, cur = 0;
    for (int t = 0; t < NT - 1; ++t) {
        stage(cur ^ 1, (t + 1) << 6);
        compute(cur);
        asm volatile("s_waitcnt vmcnt(0)" ::: "memory");
        __builtin_amdgcn_s_barrier();
        cur ^= 1;
    }
    compute(cur);

    #pragma unroll
    for (int i = 0; i < 2; i++) {
        #pragma unroll
        for (int rr = 0; rr < 4; rr++) {
            int row = row0 + w * 32 + i * 16 + ((lane >> 4) << 2) + rr;
            if (row >= M) continue;
            #pragma unroll
            for (int j = 0; j < NJ; j++) {
                int col = col0 + j * 16 + (lane & 15);
                float v = acc[i][j][rr] + (bias ? bias[col] : 0.f);
                if (relu) v = fmaxf(v, 0.f);
                storeC(C, (size_t)row * ldc + col, v);
            }
        }
    }
}

// ---------------- attention logits: wave per node, 4 ch/lane ----------------
__global__ __launch_bounds__(256) void logits_kernel(
    const unsigned short* __restrict__ hbuf,
    const float* __restrict__ a_src, const float* __restrict__ a_dst,
    float* __restrict__ al, float* __restrict__ ar)
{
    int w = threadIdx.x >> 6;
    int n = blockIdx.x * 4 + w;
    if (n >= NN) return;
    int lane = threadIdx.x & 63;
    int c4 = lane * 4;                     // global channel (head = c4>>6)
    us4 hv = *(const us4*)&hbuf[(size_t)n * 256 + c4];
    fx4 asv = *(const fx4*)&a_src[c4];
    fx4 adv = *(const fx4*)&a_dst[c4];
    float ps = 0.f, pd = 0.f;
    #pragma unroll
    for (int k = 0; k < 4; k++) {
        float h = bf2f(hv[k]);
        ps += h * asv[k];
        pd += h * adv[k];
    }
    #pragma unroll
    for (int off = 8; off; off >>= 1) {     // reduce within 16-lane head group
        ps += __shfl_xor(ps, off);
        pd += __shfl_xor(pd, off);
    }
    if ((lane & 15) == 0) {
        al[n * 4 + (lane >> 4)] = ps;
        ar[n * 4 + (lane >> 4)] = pd;
    }
}

// ---------------- GAT aggregation: wave per node, 4 ch/lane, unroll-4 ----------------
__global__ __launch_bounds__(256) void aggregate_kernel(
    const unsigned short* __restrict__ hbuf,
    const float* __restrict__ al, const float* __restrict__ ar,
    const int* __restrict__ indptr, const int* __restrict__ esrc,
    const float* __restrict__ bias,
    unsigned short* __restrict__ out, int ldo)
{
    int w = threadIdx.x >> 6;
    int n = blockIdx.x * 4 + w;
    if (n >= NN) return;
    int lane = threadIdx.x & 63;
    int myh = lane >> 4;
    int c4 = lane * 4;
    int beg = indptr[n], end = indptr[n + 1];

    fx4 arn = *(const fx4*)&ar[(size_t)n * 4];

    // pass 1: per-head max, edge-parallel over lanes
    fx4 mv = (fx4){-1e30f, -1e30f, -1e30f, -1e30f};
    for (int j = beg + lane; j < end; j += 64) {
        fx4 a = *(const fx4*)&al[(size_t)esrc[j] * 4];
        #pragma unroll
        for (int h = 0; h < 4; h++) {
            float e = a[h] + arn[h];
            e = e > 0.f ? e : 0.2f * e;
            mv[h] = fmaxf(mv[h], e);
        }
    }
    #pragma unroll
    for (int off = 32; off; off >>= 1) {
        #pragma unroll
        for (int h = 0; h < 4; h++) mv[h] = fmaxf(mv[h], __shfl_xor(mv[h], off));
    }
    float m = mv[myh];
    float arh = arn[myh];

    // pass 2: serial over edges, lane covers 4 channels of its head; unroll 4
    float ssum = 0.f;
    fx4 acc = (fx4){0.f, 0.f, 0.f, 0.f};
    int j = beg;
    for (; j + 4 <= end; j += 4) {
        int s0 = esrc[j], s1 = esrc[j + 1], s2 = esrc[j + 2], s3 = esrc[j + 3];
        us4 h0 = *(const us4*)&hbuf[(size_t)s0 * 256 + c4];
        us4 h1 = *(const us4*)&hbuf[(size_t)s1 * 256 + c4];
        us4 h2 = *(const us4*)&hbuf[(size_t)s2 * 256 + c4];
        us4 h3 = *(const us4*)&hbuf[(size_t)s3 * 256 + c4];
        float a0 = al[(size_t)s0 * 4 + myh];
        float a1 = al[(size_t)s1 * 4 + myh];
        float a2 = al[(size_t)s2 * 4 + myh];
        float a3 = al[(size_t)s3 * 4 + myh];
        float e0 = a0 + arh; e0 = e0 > 0.f ? e0 : 0.2f * e0;
        float e1 = a1 + arh; e1 = e1 > 0.f ? e1 : 0.2f * e1;
        float e2 = a2 + arh; e2 = e2 > 0.f ? e2 : 0.2f * e2;
        float e3 = a3 + arh; e3 = e3 > 0.f ? e3 : 0.2f * e3;
        float x0 = __expf(e0 - m), x1 = __expf(e1 - m);
        float x2 = __expf(e2 - m), x3 = __expf(e3 - m);
        ssum += x0 + x1 + x2 + x3;
        #pragma unroll
        for (int k = 0; k < 4; k++)
            acc[k] += x0 * bf2f(h0[k]) + x1 * bf2f(h1[k])
                    + x2 * bf2f(h2[k]) + x3 * bf2f(h3[k]);
    }
    for (; j < end; j++) {
        int s = esrc[j];
        us4 hv = *(const us4*)&hbuf[(size_t)s * 256 + c4];
        float a = al[(size_t)s * 4 + myh];
        float e = a + arh; e = e > 0.f ? e : 0.2f * e;
        float ex = __expf(e - m);
        ssum += ex;
        #pragma unroll
        for (int k = 0; k < 4; k++) acc[k] += ex * bf2f(hv[k]);
    }

    float inv = 1.f / (ssum + 1e-16f);
    us4 o;
    #pragma unroll
    for (int k = 0; k < 4; k++) o[k] = f2bf(acc[k] * inv + bias[c4 + k]);
    *(us4*)&out[(size_t)n * ldo + c4] = o;
}

// ---------------- output gathers ----------------
__global__ void gather_feats(const float* __restrict__ Bf, const float* __restrict__ Tf,
                             const int* __restrict__ voc, const int* __restrict__ batch,
                             float* __restrict__ out)
{
    int i = blockIdx.x * blockDim.x + threadIdx.x;
    if (i < NN * 128) {
        int n = i >> 7, c = i & 127;
        int t = voc[n];
        out[i] = Bf[(long)t * 128 + c];
        out[(long)NN * 128 + i] = Tf[(long)t * 128 + c];
    }
    if (i < NN) out[(long)NN * 128 * 2 + (long)NN * 64 + i] = (float)batch[i];
}

// ---------------- host-side orchestration ----------------
extern "C" void kernel_launch(void* const* d_in, const int* in_sizes, int n_in,
                              void* d_out, int out_size, void* d_ws, size_t ws_size,
                              hipStream_t stream) {
    const float* x     = (const float*)d_in[0];
    const int*   ei    = (const int*)d_in[1];
    const int*   batch = (const int*)d_in[2];
    const int*   voc   = (const int*)d_in[3];
    const float* Bf    = (const float*)d_in[4];
    const float* Tf    = (const float*)d_in[5];
    const float* W0    = (const float*)d_in[6];
    const float* as0   = (const float*)d_in[7];
    const float* ad0   = (const float*)d_in[8];
    const float* b0    = (const float*)d_in[9];
    const float* W1    = (const float*)d_in[10];
    const float* as1   = (const float*)d_in[11];
    const float* ad1   = (const float*)d_in[12];
    const float* b1    = (const float*)d_in[13];
    const float* W2    = (const float*)d_in[14];
    const float* as2   = (const float*)d_in[15];
    const float* ad2   = (const float*)d_in[16];
    const float* b2    = (const float*)d_in[17];
    const float* fcmax_w = (const float*)d_in[18];
    const float* fcmax_b = (const float*)d_in[19];
    const float* fc1_w = (const float*)d_in[20];
    const float* fc1_b = (const float*)d_in[21];
    const float* fc2_w = (const float*)d_in[22];
    const float* fc2_b = (const float*)d_in[23];
    const float* fc3_w = (const float*)d_in[24];
    const float* fc3_b = (const float*)d_in[25];
    float* out = (float*)d_out;

    char* p = (char*)d_ws;
    unsigned short* xb  = (unsigned short*)p; p += (size_t)NPAD * 128 * 2;
    unsigned short* hbuf= (unsigned short*)p; p += (size_t)NN * 256 * 2;
    unsigned short* z   = (unsigned short*)p; p += (size_t)NPAD * 1536 * 2;
    unsigned short* z1  = (unsigned short*)p; p += (size_t)NPAD * 512 * 2;
    unsigned short* h2  = (unsigned short*)p; p += (size_t)NPAD * 128 * 2;
    unsigned short* w0t = (unsigned short*)p; p += (size_t)128 * 256 * 2;
    unsigned short* w1t = (unsigned short*)p; p += (size_t)256 * 256 * 2;
    unsigned short* w2t = (unsigned short*)p; p += (size_t)256 * 256 * 2;
    unsigned short* wmt = (unsigned short*)p; p += (size_t)256 * 256 * 2;
    unsigned short* f1t = (unsigned short*)p; p += (size_t)1536 * 512 * 2;
    unsigned short* f2t = (unsigned short*)p; p += (size_t)512 * 128 * 2;
    unsigned short* f3t = (unsigned short*)p; p += (size_t)128 * 64 * 2;
    float* al   = (float*)p; p += (size_t)NN * 4 * 4;
    float* ar   = (float*)p; p += (size_t)NN * 4 * 4;
    int* cnt    = (int*)p;   p += (size_t)NN * 4;
    int* cursor = (int*)p;   p += (size_t)NN * 4;
    int* esrc   = (int*)p;   p += (size_t)ET * 4;
    int* indptr = (int*)p;   p += (size_t)(NN + 1) * 4;

    const int* e_src = ei;
    const int* e_dst = ei + EE;

    // ---- pre-pass: weights -> bf16 transposed, x -> bf16 ----
    transpose_bf16<<<dim3(4, 8),  256, 0, stream>>>(W0, w0t, 128, 256);
    transpose_bf16<<<dim3(8, 8),  256, 0, stream>>>(W1, w1t, 256, 256);
    transpose_bf16<<<dim3(8, 8),  256, 0, stream>>>(W2, w2t, 256, 256);
    transpose_bf16<<<dim3(8, 8),  256, 0, stream>>>(fcmax_w, wmt, 256, 256);
    transpose_bf16<<<dim3(48, 16),256, 0, stream>>>(fc1_w, f1t, 1536, 512);
    transpose_bf16<<<dim3(16, 4), 256, 0, stream>>>(fc2_w, f2t, 512, 128);
    transpose_bf16<<<dim3(4, 2),  256, 0, stream>>>(fc3_w, f3t, 128, 64);
    cvt_bf16_v4<<<(NN * 32 + 255) / 256, 256, 0, stream>>>(x, xb, NN * 32);

    // ---- CSR (dst-sorted incoming edges, incl. self-loops) ----
    count_init<<<(NN + 255) / 256, 256, 0, stream>>>(cnt);
    count_edges<<<(EE + 255) / 256, 256, 0, stream>>>(e_dst, cnt);
    scan_kernel<<<1, 1024, 0, stream>>>(cnt, indptr, cursor);
    scatter_self<<<(NN + 255) / 256, 256, 0, stream>>>(cursor, esrc);
    scatter_edges<<<(EE + 255) / 256, 256, 0, stream>>>(e_src, e_dst, cursor, esrc);

    // ---- independent output gathers ----
    gather_feats<<<(NN * 128 + 255) / 256, 256, 0, stream>>>(Bf, Tf, voc, batch, out);

    const int MB = NPAD / 128;  // 157
    const int NB4 = (NN + 3) / 4;  // 5000

    // ---- GAT layer 0 ----
    mfma_gemm<64, unsigned short><<<4 * MB, 256, 0, stream>>>(xb, 128, w0t, 128, hbuf, 256, NN, 128, nullptr, 0, 4);
    logits_kernel<<<NB4, 256, 0, stream>>>(hbuf, as0, ad0, al, ar);
    aggregate_kernel<<<NB4, 256, 0, stream>>>(hbuf, al, ar, indptr, esrc, b0, z + 0, 1536);
    mfma_gemm<64, unsigned short><<<4 * MB, 256, 0, stream>>>(z + 0, 1536, wmt, 256, z + 256, 1536, NN, 256, fcmax_b, 1, 4);

    // ---- GAT layer 1 ----
    mfma_gemm<64, unsigned short><<<4 * MB, 256, 0, stream>>>(z + 256, 1536, w1t, 256, hbuf, 256, NN, 256, nullptr, 0, 4);
    logits_kernel<<<NB4, 256, 0, stream>>>(hbuf, as1, ad1, al, ar);
    aggregate_kernel<<<NB4, 256, 0, stream>>>(hbuf, al, ar, indptr, esrc, b1, z + 512, 1536);
    mfma_gemm<64, unsigned short><<<4 * MB, 256, 0, stream>>>(z + 512, 1536, wmt, 256, z + 768, 1536, NN, 256, fcmax_b, 1, 4);

    // ---- GAT layer 2 ----
    mfma_gemm<64, unsigned short><<<4 * MB, 256, 0, stream>>>(z + 768, 1536, w2t, 256, hbuf, 256, NN, 256, nullptr, 0, 4);
    logits_kernel<<<NB4, 256, 0, stream>>>(hbuf, as2, ad2, al, ar);
    aggregate_kernel<<<NB4, 256, 0, stream>>>(hbuf, al, ar, indptr, esrc, b2, z + 1024, 1536);
    mfma_gemm<64, unsigned short><<<4 * MB, 256, 0, stream>>>(z + 1024, 1536, wmt, 256, z + 1280, 1536, NN, 256, fcmax_b, 1, 4);

    // ---- MLP head ----
    mfma_gemm<128, unsigned short><<<4 * MB, 256, 0, stream>>>(z, 1536, f1t, 1536, z1, 512, NN, 1536, fc1_b, 1, 4);
    mfma_gemm<64, unsigned short><<<2 * MB, 256, 0, stream>>>(z1, 512, f2t, 512, h2, 128, NN, 512, fc2_b, 1, 2);
    mfma_gemm<64, float><<<1 * MB, 256, 0, stream>>>(h2, 128, f3t, 128, out + (size_t)2 * NN * 128, 64, NN, 128, fc3_b, 0, 1);
}